// Round 2
// baseline (4062.995 us; speedup 1.0000x reference)
//
#include <hip/hip_runtime.h>
#include <hip/hip_bf16.h>

typedef unsigned short u16;

#define NPIX  65536
#define HH    256
#define WW    256
#define BATCH 2
#define CDIM  192
#define NHEADS 4
#define HD    48
#define HIDN  510
#define OPAD  1024

// ---------- helpers ----------
__device__ __forceinline__ float bf2f(u16 b) {
  union { unsigned u; float f; } v; v.u = ((unsigned)b) << 16; return v.f;
}
__device__ __forceinline__ u16 f2bf(float f) {
  union { float f; unsigned u; } v; v.f = f;
  unsigned r = v.u + 0x7fffu + ((v.u >> 16) & 1u);
  return (u16)(r >> 16);
}
__device__ __forceinline__ void atomAddF(float* p, float v) { unsafeAtomicAdd(p, v); }

// ---------- ws layout (bytes) ----------
#define OFF_STATS1 ((size_t)0)
#define OFF_STATS2 ((size_t)64)
#define OFF_G      ((size_t)128)                  // 2*4*48*48*4 = 73728
#define OFF_NQ     (OFF_G + 73728)                // 1536
#define OFF_NK     (OFF_NQ + 1536)                // 1536
#define ZERO_BYTES (OFF_NK + 1536)                // 76928, zeroed each launch
#define OFF_BSEG   ((size_t)77056)                // 2*192*4   = 1536
#define OFF_B2     (OFF_BSEG + 1536)              // 2*1024*4  = 8192
#define OFF_M      (OFF_B2 + 8192)                // 2*192*192*4 = 294912
#define OFF_WSEG   (OFF_M + 294912)               // 2*192*192*4 = 294912
#define OFF_W2     (OFF_WSEG + 294912)            // 2*1024*192*4 = 1572864
#define OFF_XSAVE  (OFF_W2 + 1572864)             // 2*192*256*4 = 393216
#define OFF_BIG    ((size_t)(OFF_XSAVE + 393216)) // = 2642688, 256-aligned
// BIG region: attn phase -> qkp bf16 [2][192][65536] = 50331648
//             gdfn phase -> hpre bf16 [2][1024][rows+2][256] ; yg after it

// ---------- 1. global LN stats ----------
__global__ void k_stats(const float* __restrict__ x, float* __restrict__ stats) {
  const int b = blockIdx.y;
  const float4* xb = (const float4*)(x + (size_t)b * CDIM * NPIX);
  const int n4 = CDIM * NPIX / 4;
  float s = 0.f, ss = 0.f;
  for (int i = blockIdx.x * blockDim.x + threadIdx.x; i < n4; i += gridDim.x * blockDim.x) {
    float4 v = xb[i];
    s  += v.x + v.y + v.z + v.w;
    ss += v.x*v.x + v.y*v.y + v.z*v.z + v.w*v.w;
  }
  for (int off = 32; off; off >>= 1) { s += __shfl_down(s, off); ss += __shfl_down(ss, off); }
  __shared__ float ls[4], lss[4];
  const int wid = threadIdx.x >> 6, lane = threadIdx.x & 63;
  if (lane == 0) { ls[wid] = s; lss[wid] = ss; }
  __syncthreads();
  if (threadIdx.x == 0) {
    atomAddF(&stats[b*2+0], ls[0]+ls[1]+ls[2]+ls[3]);
    atomAddF(&stats[b*2+1], lss[0]+lss[1]+lss[2]+lss[3]);
  }
}

// ---------- 2a. fold LN into a 192-row weight segment (two 96-row source spans) ----------
__global__ void k_fold_seg(const float* __restrict__ w_in, const float* __restrict__ ln_w,
                           const float* __restrict__ ln_b, const float* __restrict__ stats,
                           float* __restrict__ w_eff, float* __restrict__ bias,
                           int o0, int o1) {
  const int o = blockIdx.x, b = blockIdx.y, c = threadIdx.x;
  const int so = (o < 96) ? (o0 + o) : (o1 + o - 96);
  const float n = (float)(CDIM * NPIX);
  const float sum = stats[b*2], sumsq = stats[b*2+1];
  const float mean = sum / n;
  const float var = (sumsq - sum * sum / n) / (n - 1.f);
  const float inv = 1.f / (sqrtf(var) + 1e-6f);
  const float wi = w_in[so * CDIM + c];
  const float a  = ln_w[c] * inv;
  const float we = wi * a;
  float cb = wi * (ln_b[c] - mean * a);
  w_eff[((size_t)b * CDIM + o) * CDIM + c] = we;
  for (int off = 32; off; off >>= 1) cb += __shfl_down(cb, off);
  __shared__ float l[3];
  if ((threadIdx.x & 63) == 0) l[threadIdx.x >> 6] = cb;
  __syncthreads();
  if (threadIdx.x == 0) bias[b * CDIM + o] = l[0] + l[1] + l[2];
}

// ---------- 2b. fold LN into the full ff_in weight (padded to 1024 rows) ----------
__global__ void k_fold2(const float* __restrict__ w_in, const float* __restrict__ ln_w,
                        const float* __restrict__ ln_b, const float* __restrict__ stats,
                        float* __restrict__ w_eff, float* __restrict__ bias) {
  const int o = blockIdx.x, b = blockIdx.y, c = threadIdx.x;
  const float n = (float)(CDIM * NPIX);
  const float sum = stats[b*2], sumsq = stats[b*2+1];
  const float mean = sum / n;
  const float var = (sumsq - sum * sum / n) / (n - 1.f);
  const float inv = 1.f / (sqrtf(var) + 1e-6f);
  float we = 0.f, cb = 0.f;
  if (o < 1020) {
    float wi = w_in[o * CDIM + c];
    float a  = ln_w[c] * inv;
    we = wi * a;
    cb = wi * (ln_b[c] - mean * a);
  }
  w_eff[((size_t)b * OPAD + o) * CDIM + c] = we;
  for (int off = 32; off; off >>= 1) cb += __shfl_down(cb, off);
  __shared__ float l[3];
  if ((threadIdx.x & 63) == 0) l[threadIdx.x >> 6] = cb;
  __syncthreads();
  if (threadIdx.x == 0) bias[b * OPAD + o] = l[0] + l[1] + l[2];
}

// ---------- 3. GEMM-A: out[b,o,n] = sum_c Wseg[b,o,c]*x[b,c,n] + bias (f32 in, bf16 out)
__global__ __launch_bounds__(256) void k_gemm_a(const float* __restrict__ x,
                                                const float* __restrict__ w_eff,
                                                const float* __restrict__ bias,
                                                u16* __restrict__ out) {
  __shared__ u16 xs[CDIM][256];
  __shared__ float wl[CDIM][36];
  const int b = blockIdx.y;
  const int n0 = blockIdx.x * 256;
  const int tid = threadIdx.x;
  const int og = tid >> 6, ng = tid & 63;

  const float* xb = x + (size_t)b * CDIM * NPIX + n0;
  for (int idx = tid; idx < CDIM * 64; idx += 256) {
    int c = idx >> 6, j = idx & 63;
    float4 v = *(const float4*)(xb + ((size_t)c << 16) + j * 4);
    ushort4 u; u.x = f2bf(v.x); u.y = f2bf(v.y); u.z = f2bf(v.z); u.w = f2bf(v.w);
    *(ushort4*)&xs[c][j * 4] = u;
  }
  const float* wb = w_eff + (size_t)b * CDIM * CDIM;
  const float* bb = bias + b * CDIM;

  for (int oc = 0; oc < CDIM; oc += 32) {
    __syncthreads();
    for (int idx = tid; idx < 32 * CDIM; idx += 256) {
      int op = idx / CDIM, c = idx % CDIM;
      wl[c][op] = wb[(size_t)(oc + op) * CDIM + c];
    }
    __syncthreads();
    float acc[8][4];
    #pragma unroll
    for (int i = 0; i < 8; ++i) { acc[i][0]=0.f; acc[i][1]=0.f; acc[i][2]=0.f; acc[i][3]=0.f; }
    #pragma unroll 2
    for (int c = 0; c < CDIM; ++c) {
      ushort4 u = *(const ushort4*)&xs[c][ng * 4];
      float x0 = bf2f(u.x), x1 = bf2f(u.y), x2v = bf2f(u.z), x3v = bf2f(u.w);
      const float* wp = &wl[c][og * 8];
      #pragma unroll
      for (int i = 0; i < 8; ++i) {
        float wv = wp[i];
        acc[i][0] += wv * x0; acc[i][1] += wv * x1;
        acc[i][2] += wv * x2v; acc[i][3] += wv * x3v;
      }
    }
    #pragma unroll
    for (int i = 0; i < 8; ++i) {
      int o = oc + og * 8 + i;
      float bv = bb[o];
      ushort4 u;
      u.x = f2bf(acc[i][0] + bv); u.y = f2bf(acc[i][1] + bv);
      u.z = f2bf(acc[i][2] + bv); u.w = f2bf(acc[i][3] + bv);
      *(ushort4*)(out + (((size_t)(b * CDIM + o)) << 16) + n0 + ng * 4) = u;
    }
  }
}

// ---------- 4. fused dw + Gram + L2 norms for one head-pair ----------
// qkp layout: [b][0:96]=q chans (hp*96+..), [96:192]=k chans. grid (128 strips, b*2+hl)
__global__ __launch_bounds__(256) void k_gram_f(const u16* __restrict__ qkp,
                                                const float* __restrict__ dww,
                                                float* __restrict__ G,
                                                float* __restrict__ nq,
                                                float* __restrict__ nk, int hp) {
  __shared__ u16 qs[HD][520], ks[HD][520];
  __shared__ float wq[HD][9], wk[HD][9];
  const int b = blockIdx.y >> 1, hl = blockIdx.y & 1;
  const int h = hp * 2 + hl;
  const int r0 = blockIdx.x * 2;
  const int tid = threadIdx.x;

  for (int idx = tid; idx < HD * 9; idx += 256) {
    int c = idx / 9, k9 = idx % 9;
    wq[c][k9] = dww[(hp * 96 + hl * HD + c) * 9 + k9];
    wk[c][k9] = dww[(192 + hp * 96 + hl * HD + c) * 9 + k9];
  }
  __syncthreads();

  // phase 1: dw-convolve rows r0, r0+1 into LDS
  for (int idx = tid; idx < HD * 512; idx += 256) {
    const int c = idx >> 9, px = idx & 511;
    const int row = r0 + (px >> 8), col = px & 255;
    const u16* qb = qkp + (((size_t)(b * CDIM + hl * HD + c)) << 16);
    const u16* kb = qkp + (((size_t)(b * CDIM + 96 + hl * HD + c)) << 16);
    float aq = 0.f, ak = 0.f;
    #pragma unroll
    for (int dr = -1; dr <= 1; ++dr) {
      int rr = row + dr; if (rr < 0 || rr > 255) continue;
      #pragma unroll
      for (int dc = -1; dc <= 1; ++dc) {
        int cc = col + dc; if (cc < 0 || cc > 255) continue;
        float wq9 = wq[c][(dr+1)*3 + dc+1], wk9 = wk[c][(dr+1)*3 + dc+1];
        aq += wq9 * bf2f(qb[rr * 256 + cc]);
        ak += wk9 * bf2f(kb[rr * 256 + cc]);
      }
    }
    qs[c][px] = f2bf(aq); ks[c][px] = f2bf(ak);
  }
  __syncthreads();

  // phase 2: accumulate Gram + norms over 512 px
  const int tc = tid & 15, td = tid >> 4;
  float g[3][3] = {};
  float sq[3] = {}, sk[3] = {};
  for (int n = 0; n < 512; ++n) {
    float qv[3], kv[3];
    #pragma unroll
    for (int i = 0; i < 3; ++i) { qv[i] = bf2f(qs[tc*3+i][n]); kv[i] = bf2f(ks[td*3+i][n]); }
    #pragma unroll
    for (int i = 0; i < 3; ++i)
      #pragma unroll
      for (int j = 0; j < 3; ++j) g[i][j] += qv[i] * kv[j];
    if (td == 0) { sq[0] += qv[0]*qv[0]; sq[1] += qv[1]*qv[1]; sq[2] += qv[2]*qv[2]; }
    if (tc == 0) { sk[0] += kv[0]*kv[0]; sk[1] += kv[1]*kv[1]; sk[2] += kv[2]*kv[2]; }
  }
  float* Gb = G + (size_t)(b * NHEADS + h) * HD * HD;
  #pragma unroll
  for (int i = 0; i < 3; ++i)
    #pragma unroll
    for (int j = 0; j < 3; ++j) atomAddF(&Gb[(tc*3+i) * HD + td*3+j], g[i][j]);
  if (td == 0) { for (int i = 0; i < 3; ++i) atomAddF(&nq[(b*NHEADS+h)*HD + tc*3+i], sq[i]); }
  if (tc == 0) { for (int i = 0; i < 3; ++i) atomAddF(&nk[(b*NHEADS+h)*HD + td*3+i], sk[i]); }
}

// ---------- 5. normalize, softmax, combine with proj -> M[b,192,192] ----------
__global__ void k_attnM(const float* __restrict__ G, const float* __restrict__ nq,
                        const float* __restrict__ nk, const float* __restrict__ temp,
                        const float* __restrict__ proj_w, float* __restrict__ M) {
  const int h = blockIdx.x, b = blockIdx.y;
  __shared__ float at[HD][HD];
  const float* Gb = G + (size_t)(b * NHEADS + h) * HD * HD;
  const float* nqb = nq + (b * NHEADS + h) * HD;
  const float* nkb = nk + (b * NHEADS + h) * HD;
  const float t = temp[h];
  const int tid = threadIdx.x;
  for (int idx = tid; idx < HD * HD; idx += 256) {
    int c = idx / HD, d = idx % HD;
    float qn = fmaxf(sqrtf(nqb[c]), 1e-12f);
    float kn = fmaxf(sqrtf(nkb[d]), 1e-12f);
    at[c][d] = Gb[idx] / (qn * kn) * t;
  }
  __syncthreads();
  if (tid < HD) {
    float m = -1e30f;
    for (int d = 0; d < HD; ++d) m = fmaxf(m, at[tid][d]);
    float s = 0.f;
    for (int d = 0; d < HD; ++d) { float e = __expf(at[tid][d] - m); at[tid][d] = e; s += e; }
    float inv = 1.f / s;
    for (int d = 0; d < HD; ++d) at[tid][d] *= inv;
  }
  __syncthreads();
  for (int idx = tid; idx < CDIM * HD; idx += 256) {
    int o = idx / HD, d = idx % HD;
    float acc = 0.f;
    for (int c = 0; c < HD; ++c) acc += proj_w[o * CDIM + h * HD + c] * at[c][d];
    M[((size_t)b * CDIM + o) * CDIM + h * HD + d] = acc;
  }
}

// ---------- 6. x2 = x + M @ dw(v)  (writes f32 x2 into d_out, + LN2 stats) ----------
__global__ __launch_bounds__(256) void k_x2f(const u16* __restrict__ vpre,
                                             const float* __restrict__ dww,
                                             const float* __restrict__ M,
                                             const float* __restrict__ x,
                                             float* __restrict__ x2,
                                             float* __restrict__ stats2) {
  __shared__ u16 vs[CDIM][256];
  __shared__ float wl[CDIM][36];
  float* wvf = &wl[0][0];            // phase-1 alias: dw weights [192*9]
  const int b = blockIdx.y, r = blockIdx.x;
  const int tid = threadIdx.x;
  const int og = tid >> 6, ng = tid & 63;

  for (int idx = tid; idx < CDIM * 9; idx += 256) wvf[idx] = dww[384 * 9 + idx];
  __syncthreads();
  for (int idx = tid; idx < CDIM * 256; idx += 256) {
    const int ch = idx >> 8, col = idx & 255;
    const u16* vb = vpre + (((size_t)(b * CDIM + ch)) << 16);
    float a = 0.f;
    #pragma unroll
    for (int dr = -1; dr <= 1; ++dr) {
      int rr = r + dr; if (rr < 0 || rr > 255) continue;
      #pragma unroll
      for (int dc = -1; dc <= 1; ++dc) {
        int cc = col + dc; if (cc < 0 || cc > 255) continue;
        a += wvf[ch * 9 + (dr+1)*3 + dc+1] * bf2f(vb[rr * 256 + cc]);
      }
    }
    vs[ch][col] = f2bf(a);
  }
  __syncthreads();

  const float* Mb = M + (size_t)b * CDIM * CDIM;
  float lsum = 0.f, lss = 0.f;
  for (int oc = 0; oc < CDIM; oc += 32) {
    __syncthreads();
    for (int idx = tid; idx < 32 * CDIM; idx += 256) {
      int op = idx / CDIM, c = idx % CDIM;
      wl[c][op] = Mb[(size_t)(oc + op) * CDIM + c];
    }
    __syncthreads();
    float acc[8][4];
    #pragma unroll
    for (int i = 0; i < 8; ++i) { acc[i][0]=0.f; acc[i][1]=0.f; acc[i][2]=0.f; acc[i][3]=0.f; }
    #pragma unroll 2
    for (int c = 0; c < CDIM; ++c) {
      ushort4 u = *(const ushort4*)&vs[c][ng * 4];
      float x0 = bf2f(u.x), x1 = bf2f(u.y), x2v = bf2f(u.z), x3v = bf2f(u.w);
      const float* wp = &wl[c][og * 8];
      #pragma unroll
      for (int i = 0; i < 8; ++i) {
        float wv = wp[i];
        acc[i][0] += wv * x0; acc[i][1] += wv * x1;
        acc[i][2] += wv * x2v; acc[i][3] += wv * x3v;
      }
    }
    #pragma unroll
    for (int i = 0; i < 8; ++i) {
      int o = oc + og * 8 + i;
      const size_t base = (((size_t)(b * CDIM + o)) << 16) + r * 256 + ng * 4;
      float4 xr = *(const float4*)(x + base);
      float4 rr;
      rr.x = acc[i][0] + xr.x; rr.y = acc[i][1] + xr.y;
      rr.z = acc[i][2] + xr.z; rr.w = acc[i][3] + xr.w;
      *(float4*)(x2 + base) = rr;
      lsum += rr.x + rr.y + rr.z + rr.w;
      lss  += rr.x*rr.x + rr.y*rr.y + rr.z*rr.z + rr.w*rr.w;
    }
  }
  for (int off = 32; off; off >>= 1) { lsum += __shfl_down(lsum, off); lss += __shfl_down(lss, off); }
  __shared__ float r1[4], r2[4];
  if ((tid & 63) == 0) { r1[tid >> 6] = lsum; r2[tid >> 6] = lss; }
  __syncthreads();
  if (tid == 0) {
    atomAddF(&stats2[b*2+0], r1[0]+r1[1]+r1[2]+r1[3]);
    atomAddF(&stats2[b*2+1], r2[0]+r2[1]+r2[2]+r2[3]);
  }
}

// ---------- 7. GDFN gemm2: hpre band = W2 @ x2 (reads d_out rows / xsave halo) ----------
__global__ __launch_bounds__(256) void k_gemm2(const float* __restrict__ x2,
                                               const float* __restrict__ xsave,
                                               const float* __restrict__ W2,
                                               const float* __restrict__ bias2,
                                               u16* __restrict__ hpre,
                                               int rp, int rows_loc) {
  __shared__ u16 xs[CDIM][256];
  __shared__ float wl[CDIM][36];
  const int lr = blockIdx.x, b = blockIdx.z;
  const int o0 = blockIdx.y * 256;
  const int rows = rows_loc - 2;
  const int r = rp * rows - 1 + lr;
  const int tid = threadIdx.x;
  u16* hb = hpre + ((size_t)(b * OPAD + o0) * rows_loc + lr) * 256;

  if (r < 0 || r > 255) {
    ushort4 z = {0, 0, 0, 0};
    for (int idx = tid; idx < 256 * 64; idx += 256) {
      int o = idx >> 6, j = idx & 63;
      *(ushort4*)(hb + (size_t)o * rows_loc * 256 + j * 4) = z;
    }
    return;
  }
  const bool useSave = (lr == 0);
  for (int idx = tid; idx < CDIM * 64; idx += 256) {
    int c = idx >> 6, j = idx & 63;
    float4 v = useSave ? *(const float4*)(xsave + (size_t)(b * CDIM + c) * 256 + j * 4)
                       : *(const float4*)(x2 + (((size_t)(b * CDIM + c)) << 16) + r * 256 + j * 4);
    ushort4 u; u.x = f2bf(v.x); u.y = f2bf(v.y); u.z = f2bf(v.z); u.w = f2bf(v.w);
    *(ushort4*)&xs[c][j * 4] = u;
  }
  const float* wb = W2 + (size_t)b * OPAD * CDIM;
  const float* bb = bias2 + b * OPAD;
  const int og = tid >> 6, ng = tid & 63;

  for (int oc = o0; oc < o0 + 256; oc += 32) {
    __syncthreads();
    for (int idx = tid; idx < 32 * CDIM; idx += 256) {
      int op = idx / CDIM, c = idx % CDIM;
      wl[c][op] = wb[(size_t)(oc + op) * CDIM + c];
    }
    __syncthreads();
    float acc[8][4];
    #pragma unroll
    for (int i = 0; i < 8; ++i) { acc[i][0]=0.f; acc[i][1]=0.f; acc[i][2]=0.f; acc[i][3]=0.f; }
    #pragma unroll 2
    for (int c = 0; c < CDIM; ++c) {
      ushort4 u = *(const ushort4*)&xs[c][ng * 4];
      float x0 = bf2f(u.x), x1 = bf2f(u.y), x2v = bf2f(u.z), x3v = bf2f(u.w);
      const float* wp = &wl[c][og * 8];
      #pragma unroll
      for (int i = 0; i < 8; ++i) {
        float wv = wp[i];
        acc[i][0] += wv * x0; acc[i][1] += wv * x1;
        acc[i][2] += wv * x2v; acc[i][3] += wv * x3v;
      }
    }
    #pragma unroll
    for (int i = 0; i < 8; ++i) {
      int opos = oc - o0 + og * 8 + i;
      float bv = bb[oc + og * 8 + i];
      ushort4 u;
      u.x = f2bf(acc[i][0] + bv); u.y = f2bf(acc[i][1] + bv);
      u.z = f2bf(acc[i][2] + bv); u.w = f2bf(acc[i][3] + bv);
      *(ushort4*)(hb + (size_t)opos * rows_loc * 256 + ng * 4) = u;
    }
  }
}

// ---------- 8. dw + gelu gate on the band ----------
__global__ void k_dwgate(const u16* __restrict__ hp_, const float* __restrict__ w9,
                         u16* __restrict__ yg, int rows_loc) {
  const int rows = rows_loc - 2;
  const int olr0 = blockIdx.x * 4;
  const int ch = blockIdx.y, b = blockIdx.z;
  const int col = threadIdx.x;
  float wa[9], wg[9];
  #pragma unroll
  for (int i = 0; i < 9; ++i) { wa[i] = w9[ch * 9 + i]; wg[i] = w9[(ch + HIDN) * 9 + i]; }
  const u16* ia = hp_ + (size_t)(b * OPAD + ch) * rows_loc * 256;
  const u16* ig = hp_ + (size_t)(b * OPAD + ch + HIDN) * rows_loc * 256;
  float va[6][3], vg[6][3];
  #pragma unroll
  for (int rr = 0; rr < 6; ++rr) {
    int ilr = olr0 + rr;
    #pragma unroll
    for (int dc = 0; dc < 3; ++dc) {
      int cc = col - 1 + dc;
      bool ok = (cc >= 0 && cc < WW);
      va[rr][dc] = ok ? bf2f(ia[ilr * 256 + cc]) : 0.f;
      vg[rr][dc] = ok ? bf2f(ig[ilr * 256 + cc]) : 0.f;
    }
  }
  u16* ob = yg + ((size_t)(b * HIDN + ch) * rows + olr0) * 256 + col;
  #pragma unroll
  for (int k = 0; k < 4; ++k) {
    float a = 0.f, g = 0.f;
    #pragma unroll
    for (int i = 0; i < 3; ++i)
      #pragma unroll
      for (int j = 0; j < 3; ++j) {
        a += wa[i * 3 + j] * va[k + i][j];
        g += wg[i * 3 + j] * vg[k + i][j];
      }
    float gel = 0.5f * a * (1.f + erff(a * 0.70710678118654752f));
    ob[k * 256] = f2bf(gel * g);
  }
}

// ---------- 9. save one x2 row before gemm3 overwrites it ----------
__global__ void k_xsave(const float* __restrict__ x2, float* __restrict__ xsave,
                        int hi) {
  const int idx = blockIdx.x * 256 + threadIdx.x;   // idx < 2*192*256
  const int bc = idx >> 8, col = idx & 255;
  xsave[idx] = x2[(((size_t)bc) << 16) + hi * 256 + col];
}

// ---------- 10. out rows += ff_out_w @ yg (RMW on d_out holding x2) ----------
__global__ __launch_bounds__(256) void k_gemm3(const u16* __restrict__ yg,
                                               const float* __restrict__ wout,
                                               float* __restrict__ out,
                                               int rp, int rows) {
  __shared__ u16 ys[64][260];
  __shared__ float wl[64][100];
  const int b = blockIdx.z, ot = blockIdx.y, lr = blockIdx.x;
  const int r = rp * rows + lr;
  const int tid = threadIdx.x;
  const int og = tid >> 6, ng = tid & 63;
  const int o0 = ot * 96;
  float acc[3][8][4];
  #pragma unroll
  for (int c3 = 0; c3 < 3; ++c3)
    #pragma unroll
    for (int i = 0; i < 8; ++i)
      { acc[c3][i][0]=0.f; acc[c3][i][1]=0.f; acc[c3][i][2]=0.f; acc[c3][i][3]=0.f; }

  for (int cc = 0; cc < HIDN; cc += 64) {
    const int cn = (HIDN - cc < 64) ? (HIDN - cc) : 64;
    __syncthreads();
    for (int idx = tid; idx < 64 * 64; idx += 256) {
      int c = idx >> 6, j = idx & 63;
      ushort4 u = {0, 0, 0, 0};
      if (c < cn) u = *(const ushort4*)(yg + ((size_t)(b * HIDN + cc + c) * rows + lr) * 256 + j * 4);
      *(ushort4*)&ys[c][j * 4] = u;
    }
    for (int idx = tid; idx < 64 * 96; idx += 256) {
      int op = idx / 64, c = idx % 64;
      wl[c][op] = (c < cn) ? wout[(size_t)(o0 + op) * HIDN + cc + c] : 0.f;
    }
    __syncthreads();
    for (int c = 0; c < 64; ++c) {
      ushort4 u = *(const ushort4*)&ys[c][ng * 4];
      float x0 = bf2f(u.x), x1 = bf2f(u.y), x2v = bf2f(u.z), x3v = bf2f(u.w);
      #pragma unroll
      for (int c3 = 0; c3 < 3; ++c3) {
        const float* wp = &wl[c][c3 * 32 + og * 8];
        #pragma unroll
        for (int i = 0; i < 8; ++i) {
          float wv = wp[i];
          acc[c3][i][0] += wv * x0; acc[c3][i][1] += wv * x1;
          acc[c3][i][2] += wv * x2v; acc[c3][i][3] += wv * x3v;
        }
      }
    }
  }
  #pragma unroll
  for (int c3 = 0; c3 < 3; ++c3)
    #pragma unroll
    for (int i = 0; i < 8; ++i) {
      int o = o0 + c3 * 32 + og * 8 + i;
      const size_t base = (((size_t)(b * CDIM + o)) << 16) + r * 256 + ng * 4;
      float4 xr = *(const float4*)(out + base);
      float4 rr;
      rr.x = acc[c3][i][0] + xr.x; rr.y = acc[c3][i][1] + xr.y;
      rr.z = acc[c3][i][2] + xr.z; rr.w = acc[c3][i][3] + xr.w;
      *(float4*)(out + base) = rr;
    }
}

// ---------- launch ----------
extern "C" void kernel_launch(void* const* d_in, const int* in_sizes, int n_in,
                              void* d_out, int out_size, void* d_ws, size_t ws_size,
                              hipStream_t stream) {
  const float* x       = (const float*)d_in[0];
  const float* n1_w    = (const float*)d_in[1];
  const float* n1_b    = (const float*)d_in[2];
  const float* qkv_w   = (const float*)d_in[3];
  const float* qkv_dw  = (const float*)d_in[4];
  const float* proj_w  = (const float*)d_in[5];
  const float* temp    = (const float*)d_in[6];
  const float* n2_w    = (const float*)d_in[7];
  const float* n2_b    = (const float*)d_in[8];
  const float* ff_in_w = (const float*)d_in[9];
  const float* ff_dw   = (const float*)d_in[10];
  const float* ff_out_w= (const float*)d_in[11];

  char* ws = (char*)d_ws;
  float* stats1 = (float*)(ws + OFF_STATS1);
  float* stats2 = (float*)(ws + OFF_STATS2);
  float* G      = (float*)(ws + OFF_G);
  float* nq     = (float*)(ws + OFF_NQ);
  float* nk     = (float*)(ws + OFF_NK);
  float* bseg   = (float*)(ws + OFF_BSEG);
  float* bias2  = (float*)(ws + OFF_B2);
  float* M      = (float*)(ws + OFF_M);
  float* Wseg   = (float*)(ws + OFF_WSEG);
  float* W2     = (float*)(ws + OFF_W2);
  float* xsave  = (float*)(ws + OFF_XSAVE);
  u16*   qkp    = (u16*)(ws + OFF_BIG);
  float* outp   = (float*)d_out;

  // pick GDFN pass count from available workspace
  int NP = 16;
  {
    const size_t bigA = (size_t)2 * CDIM * NPIX * 2;   // 50331648
    const int cands[5] = {1, 2, 4, 8, 16};
    for (int i = 0; i < 5; ++i) {
      int rows = 256 / cands[i], rl = rows + 2;
      size_t hb = (size_t)2 * OPAD * rl * 256 * 2;
      size_t yb = (size_t)2 * HIDN * rows * 256 * 2;
      size_t big = hb + yb; if (big < bigA) big = bigA;
      if (OFF_BIG + big <= ws_size) { NP = cands[i]; break; }
    }
  }
  const int rows = 256 / NP, rows_loc = rows + 2;
  u16* hpre = (u16*)(ws + OFF_BIG);
  u16* yg   = (u16*)(ws + OFF_BIG + (size_t)2 * OPAD * rows_loc * 256 * 2);

  hipMemsetAsync(ws, 0, ZERO_BYTES, stream);

  // ---- attention ----
  k_stats<<<dim3(1024, BATCH), 256, 0, stream>>>(x, stats1);
  for (int hp = 0; hp < 2; ++hp) {
    k_fold_seg<<<dim3(CDIM, BATCH), CDIM, 0, stream>>>(qkv_w, n1_w, n1_b, stats1,
                                                       Wseg, bseg, hp * 96, 192 + hp * 96);
    k_gemm_a<<<dim3(NPIX / 256, BATCH), 256, 0, stream>>>(x, Wseg, bseg, qkp);
    k_gram_f<<<dim3(128, BATCH * 2), 256, 0, stream>>>(qkp, qkv_dw, G, nq, nk, hp);
  }
  k_attnM<<<dim3(NHEADS, BATCH), 256, 0, stream>>>(G, nq, nk, temp, proj_w, M);
  // v pass
  k_fold_seg<<<dim3(CDIM, BATCH), CDIM, 0, stream>>>(qkv_w, n1_w, n1_b, stats1,
                                                     Wseg, bseg, 384, 480);
  k_gemm_a<<<dim3(NPIX / 256, BATCH), 256, 0, stream>>>(x, Wseg, bseg, qkp);
  k_x2f<<<dim3(HH, BATCH), 256, 0, stream>>>(qkp, qkv_dw, M, x, outp, stats2);

  // ---- GDFN ----
  k_fold2<<<dim3(OPAD, BATCH), CDIM, 0, stream>>>(ff_in_w, n2_w, n2_b, stats2, W2, bias2);
  for (int rp = 0; rp < NP; ++rp) {
    k_gemm2<<<dim3(rows_loc, 4, BATCH), 256, 0, stream>>>(outp, xsave, W2, bias2,
                                                          hpre, rp, rows_loc);
    k_dwgate<<<dim3(rows / 4, HIDN, BATCH), 256, 0, stream>>>(hpre, ff_dw, yg, rows_loc);
    if (rp + 1 < NP)
      k_xsave<<<dim3(2 * CDIM, 1), 256, 0, stream>>>(outp, xsave, rp * rows + rows - 1);
    k_gemm3<<<dim3(rows, 2, BATCH), 256, 0, stream>>>(yg, ff_out_w, outp, rp, rows);
  }
}

// Round 3
// 3109.399 us; speedup vs baseline: 1.3067x; 1.3067x over previous
//
#include <hip/hip_runtime.h>
#include <hip/hip_bf16.h>

typedef unsigned short u16;
typedef __attribute__((ext_vector_type(8))) short short8;
typedef __attribute__((ext_vector_type(4))) float f32x4;

#define NPIX  65536
#define HH    256
#define WW    256
#define BATCH 2
#define CDIM  192
#define NHEADS 4
#define HD    48
#define OQKV  576
#define HIDN  510
#define OPAD  1024

// ---------- helpers ----------
__device__ __forceinline__ float bf2f(u16 b) {
  union { unsigned u; float f; } v; v.u = ((unsigned)b) << 16; return v.f;
}
__device__ __forceinline__ u16 f2bf(float f) {
  union { float f; unsigned u; } v; v.f = f;
  unsigned r = v.u + 0x7fffu + ((v.u >> 16) & 1u);
  return (u16)(r >> 16);
}
__device__ __forceinline__ void atomAddF(float* p, float v) { unsafeAtomicAdd(p, v); }
__device__ __forceinline__ void gload16(const void* g, void* l) {
  __builtin_amdgcn_global_load_lds((const __attribute__((address_space(1))) unsigned int*)g,
                                   (__attribute__((address_space(3))) unsigned int*)l, 16, 0, 0);
}

// ---------- ws layout (bytes) ----------
#define OFF_STATS1 ((size_t)0)
#define OFF_STATS2 ((size_t)64)
#define OFF_G      ((size_t)128)                  // 2*4*48*48*4 = 73728
#define OFF_NQ     (OFF_G + 73728)
#define OFF_NK     (OFF_NQ + 1536)
#define ZERO_BYTES (OFF_NK + 1536)                // 76928, zeroed each launch
#define OFF_BQ     ((size_t)77056)                // f32 [2][576]
#define OFF_B2     (OFF_BQ + 4608)                // f32 [2][1024]
#define OFF_M      (OFF_B2 + 8192)                // f32 [2][192][192]
#define OFF_WQ     (OFF_M + 294912)               // bf16 [2][576][192] preswz
#define OFF_W2B    (OFF_WQ + 442368)              // bf16 [2][1024][192] preswz
#define OFF_W3     (OFF_W2B + 786432)             // bf16 [192][512] preswz
#define OFF_T      (OFF_W3 + 196608)              // bf16 T [2][65536][192]: xT then x2T
#define OFF_QKV    (OFF_T + 50331648)             // bf16 planar [2][576][65536]
#define OFF_BAND   (OFF_QKV + 150994944)          // hpre band + ygT band

// ---------- 1. global LN stats ----------
__global__ void k_stats(const float* __restrict__ x, float* __restrict__ stats) {
  const int b = blockIdx.y;
  const float4* xb = (const float4*)(x + (size_t)b * CDIM * NPIX);
  const int n4 = CDIM * NPIX / 4;
  float s = 0.f, ss = 0.f;
  for (int i = blockIdx.x * blockDim.x + threadIdx.x; i < n4; i += gridDim.x * blockDim.x) {
    float4 v = xb[i];
    s  += v.x + v.y + v.z + v.w;
    ss += v.x*v.x + v.y*v.y + v.z*v.z + v.w*v.w;
  }
  for (int off = 32; off; off >>= 1) { s += __shfl_down(s, off); ss += __shfl_down(ss, off); }
  __shared__ float ls[4], lss[4];
  const int wid = threadIdx.x >> 6, lane = threadIdx.x & 63;
  if (lane == 0) { ls[wid] = s; lss[wid] = ss; }
  __syncthreads();
  if (threadIdx.x == 0) {
    atomAddF(&stats[b*2+0], ls[0]+ls[1]+ls[2]+ls[3]);
    atomAddF(&stats[b*2+1], lss[0]+lss[1]+lss[2]+lss[3]);
  }
}

// ---------- 2. fold LN into 1x1 weights -> bf16 preswz (key o&7) ----------
__global__ void k_fold(const float* __restrict__ w_in, const float* __restrict__ ln_w,
                       const float* __restrict__ ln_b, const float* __restrict__ stats,
                       u16* __restrict__ W, float* __restrict__ bias, int O_real) {
  const int o = blockIdx.x, b = blockIdx.y, c = threadIdx.x;
  const int Mtot = gridDim.x;
  const float n = (float)(CDIM * NPIX);
  const float sum = stats[b*2], sumsq = stats[b*2+1];
  const float mean = sum / n;
  const float var = (sumsq - sum * sum / n) / (n - 1.f);
  const float inv = 1.f / (sqrtf(var) + 1e-6f);
  float we = 0.f, cb = 0.f;
  if (o < O_real) {
    float wi = w_in[o * CDIM + c];
    float a  = ln_w[c] * inv;
    we = wi * a;
    cb = wi * (ln_b[c] - mean * a);
  }
  int sch = (c >> 3) ^ (o & 7);
  W[((size_t)b * Mtot + o) * CDIM + sch * 8 + (c & 7)] = f2bf(we);
  for (int off = 32; off; off >>= 1) cb += __shfl_down(cb, off);
  __shared__ float l[3];
  if ((threadIdx.x & 63) == 0) l[threadIdx.x >> 6] = cb;
  __syncthreads();
  if (threadIdx.x == 0) bias[b * Mtot + o] = l[0] + l[1] + l[2];
}

// ---------- 2b. ff_out weights -> bf16 [192][512] preswz ----------
__global__ void k_fold3(const float* __restrict__ w, u16* __restrict__ W3) {
  const int o = blockIdx.x;
  for (int it = 0; it < 2; ++it) {
    int c = it * 256 + threadIdx.x;
    float v = (c < HIDN) ? w[o * HIDN + c] : 0.f;
    int sch = (c >> 3) ^ (o & 7);
    W3[o * 512 + sch * 8 + (c & 7)] = f2bf(v);
  }
}

// ---------- 3. transpose f32 planar [b][192][n] -> bf16 T [b][n][192] preswz ----------
__global__ __launch_bounds__(256) void k_tr(const float* __restrict__ P, u16* __restrict__ T) {
  __shared__ u16 ld[128][200];
  const int b = blockIdx.y, n0 = blockIdx.x * 128, tid = threadIdx.x;
  const float* Pb = P + (((size_t)b * CDIM) << 16) + n0;
  for (int it = 0; it < 96; ++it) {
    int idx = it * 256 + tid;
    int nl = idx & 127, c = idx >> 7;
    ld[nl][c] = f2bf(Pb[((size_t)c << 16) + nl]);
  }
  __syncthreads();
  u16* Tb = T + (size_t)(b * NPIX + n0) * CDIM;
  for (int it = 0; it < 12; ++it) {
    int idx = it * 256 + tid;
    int ch = idx % 24, nl = idx / 24;
    union { u16 s[8]; uint4 v; } t;
    #pragma unroll
    for (int r = 0; r < 8; ++r) t.s[r] = ld[nl][ch * 8 + r];
    int sch = ch ^ (nl & 7);
    *(uint4*)((char*)(Tb + (size_t)nl * CDIM) + sch * 16) = t.v;
  }
}

// ---------- 4. MFMA GEMM: out[b,o,n] = sum_c A[b,o,c]*B[b,n,c] ----------
// A,B bf16 preswz (A key o&7, B key n&7). Tile 64(o) x 128(n), 4 waves.
// EPI=0: bf16 planar out + bias. EPI=1: f32 out = acc + resid (in-place ok).
template <int KTOT, int KC, int EPI>
__global__ __launch_bounds__(256) void k_mgemm(
    const u16* __restrict__ Bm, const u16* __restrict__ Am,
    const float* __restrict__ bias, const float* __restrict__ resid,
    void* __restrict__ outv, int Mtot,
    long Bbstr, long Abstr, long Obstr, int out_nstr,
    int nB_base, int nB_rows, int nO_base)
{
  constexpr int RBC = KC * 2;
  __shared__ u16 lB[128 * KC];
  __shared__ u16 lA[64 * KC];
  const int b = blockIdx.z;
  const int o0 = blockIdx.x * 64;
  const int nB = nB_base + blockIdx.y * 128;
  const int nO = nO_base + blockIdx.y * 128;
  const int tid = threadIdx.x;
  const int lane = tid & 63;
  const int wid = tid >> 6;

  if (EPI == 0 && (nB < 0 || nB >= nB_rows)) {     // halo block outside image: zeros
    u16* op = (u16*)outv;
    uint4 z; z.x = z.y = z.z = z.w = 0u;
    for (int it = 0; it < 4; ++it) {
      int idx = it * 256 + tid;
      int orow = idx >> 4, c8 = idx & 15;
      *(uint4*)(op + (size_t)b * Obstr + (size_t)(o0 + orow) * out_nstr + nO + c8 * 8) = z;
    }
    return;
  }

  const u16* Bb = Bm + (size_t)b * Bbstr + (size_t)nB * KTOT;
  const u16* Ab = Am + (size_t)b * Abstr + (size_t)o0 * KTOT;

  f32x4 acc[4][2];
  #pragma unroll
  for (int m = 0; m < 4; ++m)
    #pragma unroll
    for (int nf = 0; nf < 2; ++nf) acc[m][nf] = (f32x4){0.f, 0.f, 0.f, 0.f};

  for (int kc0 = 0; kc0 < KTOT; kc0 += KC) {
    if (kc0) __syncthreads();
    if constexpr (KTOT == KC) {       // full rows: pure linear copy
      #pragma unroll
      for (int it = 0; it < 128 * RBC / 16 / 256; ++it) {
        int idx = it * 256 + tid;
        gload16((const char*)Bb + idx * 16, (char*)lB + idx * 16);
      }
      #pragma unroll
      for (int it = 0; it < 64 * RBC / 16 / 256; ++it) {
        int idx = it * 256 + tid;
        gload16((const char*)Ab + idx * 16, (char*)lA + idx * 16);
      }
    } else {                          // row segments
      constexpr int NCH = KC / 8;
      #pragma unroll
      for (int it = 0; it < 128 * NCH / 256; ++it) {
        int idx = it * 256 + tid; int r = idx / NCH, ch = idx % NCH;
        gload16((const char*)(Bb + (size_t)r * KTOT + kc0) + ch * 16, (char*)lB + idx * 16);
      }
      #pragma unroll
      for (int it = 0; it < 64 * NCH / 256; ++it) {
        int idx = it * 256 + tid; int r = idx / NCH, ch = idx % NCH;
        gload16((const char*)(Ab + (size_t)r * KTOT + kc0) + ch * 16, (char*)lA + idx * 16);
      }
    }
    __syncthreads();
    const int lr = lane & 15, g = lane >> 4;
    #pragma unroll
    for (int ks = 0; ks < KC / 32; ++ks) {
      const int ck = ks * 4 + g;
      short8 afr[4], bfr[2];
      #pragma unroll
      for (int m = 0; m < 4; ++m) {
        int row = m * 16 + lr;
        afr[m] = *(const short8*)((const char*)lA + row * RBC + ((ck ^ (row & 7)) << 4));
      }
      #pragma unroll
      for (int nf = 0; nf < 2; ++nf) {
        int row = wid * 32 + nf * 16 + lr;
        bfr[nf] = *(const short8*)((const char*)lB + row * RBC + ((ck ^ (row & 7)) << 4));
      }
      #pragma unroll
      for (int m = 0; m < 4; ++m)
        #pragma unroll
        for (int nf = 0; nf < 2; ++nf)
          acc[m][nf] = __builtin_amdgcn_mfma_f32_16x16x32_bf16(afr[m], bfr[nf], acc[m][nf], 0, 0, 0);
    }
  }

  const int col = lane & 15, rg = lane >> 4;
  if (EPI == 0) {
    u16* op = (u16*)outv;
    #pragma unroll
    for (int m = 0; m < 4; ++m)
      #pragma unroll
      for (int j = 0; j < 4; ++j) {
        int o = o0 + m * 16 + rg * 4 + j;
        float bv = bias[b * Mtot + o];
        #pragma unroll
        for (int nf = 0; nf < 2; ++nf) {
          int nn = nO + wid * 32 + nf * 16 + col;
          op[(size_t)b * Obstr + (size_t)o * out_nstr + nn] = f2bf(acc[m][nf][j] + bv);
        }
      }
  } else {
    float* of = (float*)outv;
    #pragma unroll
    for (int m = 0; m < 4; ++m)
      #pragma unroll
      for (int nf = 0; nf < 2; ++nf)
        #pragma unroll
        for (int j = 0; j < 4; ++j) {
          int o = o0 + m * 16 + rg * 4 + j;
          int nn = nO + wid * 32 + nf * 16 + col;
          size_t ix = (size_t)b * Obstr + (size_t)o * out_nstr + nn;
          of[ix] = acc[m][nf][j] + resid[ix];
        }
  }
}

// ---------- 5. fused dw + Gram + L2 norms, one head per block-row ----------
__global__ __launch_bounds__(256) void k_gram_f(const u16* __restrict__ qkv,
                                                const float* __restrict__ dww,
                                                float* __restrict__ G,
                                                float* __restrict__ nq,
                                                float* __restrict__ nk) {
  __shared__ u16 qs[HD][520], ks[HD][520];
  __shared__ float wq[HD][9], wk[HD][9];
  const int b = blockIdx.y >> 2, h = blockIdx.y & 3;
  const int r0 = blockIdx.x * 2;
  const int tid = threadIdx.x;

  for (int idx = tid; idx < HD * 9; idx += 256) {
    int c = idx / 9, k9 = idx % 9;
    wq[c][k9] = dww[(h * HD + c) * 9 + k9];
    wk[c][k9] = dww[(CDIM + h * HD + c) * 9 + k9];
  }
  __syncthreads();

  for (int idx = tid; idx < HD * 512; idx += 256) {
    const int c = idx >> 9, px = idx & 511;
    const int row = r0 + (px >> 8), col = px & 255;
    const u16* qb = qkv + (((size_t)(b * OQKV + h * HD + c)) << 16);
    const u16* kb = qkv + (((size_t)(b * OQKV + CDIM + h * HD + c)) << 16);
    float aq = 0.f, ak = 0.f;
    #pragma unroll
    for (int dr = -1; dr <= 1; ++dr) {
      int rr = row + dr; if (rr < 0 || rr > 255) continue;
      #pragma unroll
      for (int dc = -1; dc <= 1; ++dc) {
        int cc = col + dc; if (cc < 0 || cc > 255) continue;
        float wq9 = wq[c][(dr+1)*3 + dc+1], wk9 = wk[c][(dr+1)*3 + dc+1];
        aq += wq9 * bf2f(qb[rr * 256 + cc]);
        ak += wk9 * bf2f(kb[rr * 256 + cc]);
      }
    }
    qs[c][px] = f2bf(aq); ks[c][px] = f2bf(ak);
  }
  __syncthreads();

  const int tc = tid & 15, td = tid >> 4;
  float g[3][3] = {};
  float sq[3] = {}, sk[3] = {};
  for (int n = 0; n < 512; ++n) {
    float qv[3], kv[3];
    #pragma unroll
    for (int i = 0; i < 3; ++i) { qv[i] = bf2f(qs[tc*3+i][n]); kv[i] = bf2f(ks[td*3+i][n]); }
    #pragma unroll
    for (int i = 0; i < 3; ++i)
      #pragma unroll
      for (int j = 0; j < 3; ++j) g[i][j] += qv[i] * kv[j];
    if (td == 0) { sq[0] += qv[0]*qv[0]; sq[1] += qv[1]*qv[1]; sq[2] += qv[2]*qv[2]; }
    if (tc == 0) { sk[0] += kv[0]*kv[0]; sk[1] += kv[1]*kv[1]; sk[2] += kv[2]*kv[2]; }
  }
  float* Gb = G + (size_t)(b * NHEADS + h) * HD * HD;
  #pragma unroll
  for (int i = 0; i < 3; ++i)
    #pragma unroll
    for (int j = 0; j < 3; ++j) atomAddF(&Gb[(tc*3+i) * HD + td*3+j], g[i][j]);
  if (td == 0) { for (int i = 0; i < 3; ++i) atomAddF(&nq[(b*NHEADS+h)*HD + tc*3+i], sq[i]); }
  if (tc == 0) { for (int i = 0; i < 3; ++i) atomAddF(&nk[(b*NHEADS+h)*HD + td*3+i], sk[i]); }
}

// ---------- 6. normalize, softmax, combine with proj -> M[b,192,192] f32 ----------
__global__ void k_attnM(const float* __restrict__ G, const float* __restrict__ nq,
                        const float* __restrict__ nk, const float* __restrict__ temp,
                        const float* __restrict__ proj_w, float* __restrict__ M) {
  const int h = blockIdx.x, b = blockIdx.y;
  __shared__ float at[HD][HD];
  const float* Gb = G + (size_t)(b * NHEADS + h) * HD * HD;
  const float* nqb = nq + (b * NHEADS + h) * HD;
  const float* nkb = nk + (b * NHEADS + h) * HD;
  const float t = temp[h];
  const int tid = threadIdx.x;
  for (int idx = tid; idx < HD * HD; idx += 256) {
    int c = idx / HD, d = idx % HD;
    float qn = fmaxf(sqrtf(nqb[c]), 1e-12f);
    float kn = fmaxf(sqrtf(nkb[d]), 1e-12f);
    at[c][d] = Gb[idx] / (qn * kn) * t;
  }
  __syncthreads();
  if (tid < HD) {
    float m = -1e30f;
    for (int d = 0; d < HD; ++d) m = fmaxf(m, at[tid][d]);
    float s = 0.f;
    for (int d = 0; d < HD; ++d) { float e = __expf(at[tid][d] - m); at[tid][d] = e; s += e; }
    float inv = 1.f / s;
    for (int d = 0; d < HD; ++d) at[tid][d] *= inv;
  }
  __syncthreads();
  for (int idx = tid; idx < CDIM * HD; idx += 256) {
    int o = idx / HD, d = idx % HD;
    float acc = 0.f;
    for (int c = 0; c < HD; ++c) acc += proj_w[o * CDIM + h * HD + c] * at[c][d];
    M[((size_t)b * CDIM + o) * CDIM + h * HD + d] = acc;
  }
}

// ---------- 7. x2 = x + M @ dw(v)  (f32 x2 -> d_out, + LN2 stats) ----------
__global__ __launch_bounds__(256) void k_x2f(const u16* __restrict__ qkv,
                                             const float* __restrict__ dww,
                                             const float* __restrict__ M,
                                             const float* __restrict__ x,
                                             float* __restrict__ x2,
                                             float* __restrict__ stats2) {
  __shared__ u16 vs[CDIM][256];
  __shared__ float wl[CDIM][36];
  float* wvf = &wl[0][0];
  const int b = blockIdx.y, r = blockIdx.x;
  const int tid = threadIdx.x;
  const int og = tid >> 6, ng = tid & 63;

  for (int idx = tid; idx < CDIM * 9; idx += 256) wvf[idx] = dww[384 * 9 + idx];
  __syncthreads();
  for (int idx = tid; idx < CDIM * 256; idx += 256) {
    const int ch = idx >> 8, col = idx & 255;
    const u16* vb = qkv + (((size_t)(b * OQKV + 384 + ch)) << 16);
    float a = 0.f;
    #pragma unroll
    for (int dr = -1; dr <= 1; ++dr) {
      int rr = r + dr; if (rr < 0 || rr > 255) continue;
      #pragma unroll
      for (int dc = -1; dc <= 1; ++dc) {
        int cc = col + dc; if (cc < 0 || cc > 255) continue;
        a += wvf[ch * 9 + (dr+1)*3 + dc+1] * bf2f(vb[rr * 256 + cc]);
      }
    }
    vs[ch][col] = f2bf(a);
  }
  __syncthreads();

  const float* Mb = M + (size_t)b * CDIM * CDIM;
  float lsum = 0.f, lss = 0.f;
  for (int oc = 0; oc < CDIM; oc += 32) {
    __syncthreads();
    for (int idx = tid; idx < 32 * CDIM; idx += 256) {
      int op = idx / CDIM, c = idx % CDIM;
      wl[c][op] = Mb[(size_t)(oc + op) * CDIM + c];
    }
    __syncthreads();
    float acc[8][4];
    #pragma unroll
    for (int i = 0; i < 8; ++i) { acc[i][0]=0.f; acc[i][1]=0.f; acc[i][2]=0.f; acc[i][3]=0.f; }
    #pragma unroll 2
    for (int c = 0; c < CDIM; ++c) {
      ushort4 u = *(const ushort4*)&vs[c][ng * 4];
      float x0 = bf2f(u.x), x1 = bf2f(u.y), x2v = bf2f(u.z), x3v = bf2f(u.w);
      const float* wp = &wl[c][og * 8];
      #pragma unroll
      for (int i = 0; i < 8; ++i) {
        float wv = wp[i];
        acc[i][0] += wv * x0; acc[i][1] += wv * x1;
        acc[i][2] += wv * x2v; acc[i][3] += wv * x3v;
      }
    }
    #pragma unroll
    for (int i = 0; i < 8; ++i) {
      int o = oc + og * 8 + i;
      const size_t base = (((size_t)(b * CDIM + o)) << 16) + r * 256 + ng * 4;
      float4 xr = *(const float4*)(x + base);
      float4 rr;
      rr.x = acc[i][0] + xr.x; rr.y = acc[i][1] + xr.y;
      rr.z = acc[i][2] + xr.z; rr.w = acc[i][3] + xr.w;
      *(float4*)(x2 + base) = rr;
      lsum += rr.x + rr.y + rr.z + rr.w;
      lss  += rr.x*rr.x + rr.y*rr.y + rr.z*rr.z + rr.w*rr.w;
    }
  }
  for (int off = 32; off; off >>= 1) { lsum += __shfl_down(lsum, off); lss += __shfl_down(lss, off); }
  __shared__ float r1[4], r2[4];
  if ((tid & 63) == 0) { r1[tid >> 6] = lsum; r2[tid >> 6] = lss; }
  __syncthreads();
  if (tid == 0) {
    atomAddF(&stats2[b*2+0], r1[0]+r1[1]+r1[2]+r1[3]);
    atomAddF(&stats2[b*2+1], r2[0]+r2[1]+r2[2]+r2[3]);
  }
}

// ---------- 8. dw + gelu gate on hpre band -> ygT bf16 [b][band_px][512] preswz ----------
__global__ __launch_bounds__(256) void k_dwgT(const u16* __restrict__ hp_, const float* __restrict__ w9,
                                              u16* __restrict__ ygT, int rows_loc, int band_px) {
  __shared__ u16 ld[64][520];
  const int b = blockIdx.y;
  const int p0 = blockIdx.x * 64;
  const int olr = p0 >> 8, col0 = p0 & 255;
  const int tid = threadIdx.x;
  for (int it = 0; it < 128; ++it) {
    int idx = it * 256 + tid;
    int c = idx >> 6, px = idx & 63;
    float v = 0.f;
    if (c < HIDN) {
      const u16* ia = hp_ + (size_t)(b * OPAD + c) * rows_loc * 256;
      const u16* ig = hp_ + (size_t)(b * OPAD + c + HIDN) * rows_loc * 256;
      float a = 0.f, g = 0.f;
      #pragma unroll
      for (int dr = 0; dr < 3; ++dr) {
        #pragma unroll
        for (int dc = -1; dc <= 1; ++dc) {
          int cc = col0 + px + dc;
          if (cc < 0 || cc > 255) continue;
          float wa = w9[c * 9 + dr * 3 + dc + 1];
          float wg = w9[(c + HIDN) * 9 + dr * 3 + dc + 1];
          a += wa * bf2f(ia[(olr + dr) * 256 + cc]);
          g += wg * bf2f(ig[(olr + dr) * 256 + cc]);
        }
      }
      float gel = 0.5f * a * (1.f + erff(a * 0.70710678118654752f));
      v = gel * g;
    }
    ld[px][c] = f2bf(v);
  }
  __syncthreads();
  u16* Tb = ygT + ((size_t)b * band_px + p0) * 512;
  for (int it = 0; it < 16; ++it) {
    int idx = it * 256 + tid;
    int ch = idx & 63, pl = idx >> 6;
    union { u16 s[8]; uint4 v; } t;
    #pragma unroll
    for (int r = 0; r < 8; ++r) t.s[r] = ld[pl][ch * 8 + r];
    int sch = ch ^ (pl & 7);
    *(uint4*)((char*)(Tb + (size_t)pl * 512) + sch * 16) = t.v;
  }
}

// ---------- launch ----------
extern "C" void kernel_launch(void* const* d_in, const int* in_sizes, int n_in,
                              void* d_out, int out_size, void* d_ws, size_t ws_size,
                              hipStream_t stream) {
  const float* x       = (const float*)d_in[0];
  const float* n1_w    = (const float*)d_in[1];
  const float* n1_b    = (const float*)d_in[2];
  const float* qkv_w   = (const float*)d_in[3];
  const float* qkv_dw  = (const float*)d_in[4];
  const float* proj_w  = (const float*)d_in[5];
  const float* temp    = (const float*)d_in[6];
  const float* n2_w    = (const float*)d_in[7];
  const float* n2_b    = (const float*)d_in[8];
  const float* ff_in_w = (const float*)d_in[9];
  const float* ff_dw   = (const float*)d_in[10];
  const float* ff_out_w= (const float*)d_in[11];

  char* ws = (char*)d_ws;
  float* stats1 = (float*)(ws + OFF_STATS1);
  float* stats2 = (float*)(ws + OFF_STATS2);
  float* G      = (float*)(ws + OFF_G);
  float* nq     = (float*)(ws + OFF_NQ);
  float* nk     = (float*)(ws + OFF_NK);
  float* biasq  = (float*)(ws + OFF_BQ);
  float* bias2  = (float*)(ws + OFF_B2);
  float* M      = (float*)(ws + OFF_M);
  u16*   Wq     = (u16*)(ws + OFF_WQ);
  u16*   W2b    = (u16*)(ws + OFF_W2B);
  u16*   W3     = (u16*)(ws + OFF_W3);
  u16*   xT     = (u16*)(ws + OFF_T);      // xT then x2T
  u16*   qkv    = (u16*)(ws + OFF_QKV);
  float* outp   = (float*)d_out;

  // pick GDFN band count from available workspace (+8MB safety margin)
  int NP = 32;
  const int cand[4] = {2, 4, 8, 16};
  for (int i = 0; i < 4; ++i) {
    int rws = 256 / cand[i], rl = rws + 2;
    size_t band = (size_t)2 * OPAD * rl * 256 * 2 + (size_t)2 * rws * 256 * 512 * 2;
    if (OFF_BAND + band + ((size_t)8 << 20) <= ws_size) { NP = cand[i]; break; }
  }
  const int rows = 256 / NP, rows_loc = rows + 2, band_px = rows * 256;
  u16* hpre = (u16*)(ws + OFF_BAND);
  u16* ygT  = (u16*)(ws + OFF_BAND + (size_t)2 * OPAD * rows_loc * 256 * 2);

  hipMemsetAsync(ws, 0, ZERO_BYTES, stream);

  // ---- attention ----
  k_stats<<<dim3(1024, BATCH), 256, 0, stream>>>(x, stats1);
  k_fold<<<dim3(OQKV, BATCH), CDIM, 0, stream>>>(qkv_w, n1_w, n1_b, stats1, Wq, biasq, OQKV);
  k_tr<<<dim3(NPIX / 128, BATCH), 256, 0, stream>>>(x, xT);
  k_mgemm<192, 192, 0><<<dim3(OQKV / 64, NPIX / 128, BATCH), 256, 0, stream>>>(
      xT, Wq, biasq, nullptr, qkv, OQKV,
      (long)NPIX * CDIM, (long)OQKV * CDIM, (long)OQKV * NPIX, NPIX, 0, NPIX, 0);
  k_gram_f<<<dim3(128, BATCH * NHEADS), 256, 0, stream>>>(qkv, qkv_dw, G, nq, nk);
  k_attnM<<<dim3(NHEADS, BATCH), 256, 0, stream>>>(G, nq, nk, temp, proj_w, M);
  k_x2f<<<dim3(HH, BATCH), 256, 0, stream>>>(qkv, qkv_dw, M, x, outp, stats2);

  // ---- GDFN ----
  k_tr<<<dim3(NPIX / 128, BATCH), 256, 0, stream>>>(outp, xT);   // x2T (reuse region)
  k_fold<<<dim3(OPAD, BATCH), CDIM, 0, stream>>>(ff_in_w, n2_w, n2_b, stats2, W2b, bias2, 1020);
  k_fold3<<<dim3(CDIM), 256, 0, stream>>>(ff_out_w, W3);
  for (int rp = 0; rp < NP; ++rp) {
    const int band0 = rp * band_px;
    k_mgemm<192, 192, 0><<<dim3(OPAD / 64, rows_loc * 2, BATCH), 256, 0, stream>>>(
        xT, W2b, bias2, nullptr, hpre, OPAD,
        (long)NPIX * CDIM, (long)OPAD * CDIM, (long)OPAD * rows_loc * 256, rows_loc * 256,
        band0 - 256, NPIX, 0);
    k_dwgT<<<dim3(band_px / 64, BATCH), 256, 0, stream>>>(hpre, ff_dw, ygT, rows_loc, band_px);
    k_mgemm<512, 256, 1><<<dim3(CDIM / 64, rows * 2, BATCH), 256, 0, stream>>>(
        ygT, W3, nullptr, outp, outp, CDIM,
        (long)band_px * 512, 0L, (long)CDIM * NPIX, NPIX, 0, band_px, band0);
  }
}

// Round 4
// 2591.232 us; speedup vs baseline: 1.5680x; 1.2000x over previous
//
#include <hip/hip_runtime.h>
#include <hip/hip_bf16.h>

typedef unsigned short u16;
typedef __attribute__((ext_vector_type(8))) short short8;
typedef __attribute__((ext_vector_type(4))) float f32x4;

#define NPIX  65536
#define HH    256
#define WW    256
#define BATCH 2
#define CDIM  192
#define NHEADS 4
#define HD    48
#define OQKV  576
#define HIDN  510
#define OPAD  1024

// ---------- helpers ----------
__device__ __forceinline__ float bf2f(u16 b) {
  union { unsigned u; float f; } v; v.u = ((unsigned)b) << 16; return v.f;
}
__device__ __forceinline__ u16 f2bf(float f) {
  union { float f; unsigned u; } v; v.f = f;
  unsigned r = v.u + 0x7fffu + ((v.u >> 16) & 1u);
  return (u16)(r >> 16);
}
__device__ __forceinline__ void atomAddF(float* p, float v) { unsafeAtomicAdd(p, v); }
__device__ __forceinline__ void gload16(const void* g, void* l) {
  __builtin_amdgcn_global_load_lds((const __attribute__((address_space(1))) unsigned int*)g,
                                   (__attribute__((address_space(3))) unsigned int*)l, 16, 0, 0);
}

// ---------- ws layout (bytes) ----------
#define OFF_STATS1 ((size_t)0)
#define OFF_STATS2 ((size_t)64)
#define OFF_G      ((size_t)128)                  // 2*4*48*48*4 = 73728
#define OFF_NQ     (OFF_G + 73728)
#define OFF_NK     (OFF_NQ + 1536)
#define ZERO_BYTES (OFF_NK + 1536)                // 76928, zeroed each launch
#define OFF_BQ     ((size_t)77056)                // f32 [2][576]
#define OFF_B2     (OFF_BQ + 4608)                // f32 [2][1024]
#define OFF_M      (OFF_B2 + 8192)                // bf16 preswz [2][192][192] (reserved 294912)
#define OFF_WQ     (OFF_M + 294912)               // bf16 [2][576][192] preswz
#define OFF_W2B    (OFF_WQ + 442368)              // bf16 [2][1024][192] preswz
#define OFF_W3     (OFF_W2B + 786432)             // bf16 [192][512] preswz
#define OFF_T      (OFF_W3 + 196608)              // bf16 T [2][65536][192]: xT -> vdwT -> x2T
#define OFF_QKV    (OFF_T + 50331648)             // bf16 planar [2][576][65536]
#define OFF_BAND   (OFF_QKV + 150994944)          // hpre band + ygT band

// ---------- 1. global LN stats ----------
__global__ void k_stats(const float* __restrict__ x, float* __restrict__ stats) {
  const int b = blockIdx.y;
  const float4* xb = (const float4*)(x + (size_t)b * CDIM * NPIX);
  const int n4 = CDIM * NPIX / 4;
  float s = 0.f, ss = 0.f;
  for (int i = blockIdx.x * blockDim.x + threadIdx.x; i < n4; i += gridDim.x * blockDim.x) {
    float4 v = xb[i];
    s  += v.x + v.y + v.z + v.w;
    ss += v.x*v.x + v.y*v.y + v.z*v.z + v.w*v.w;
  }
  for (int off = 32; off; off >>= 1) { s += __shfl_down(s, off); ss += __shfl_down(ss, off); }
  __shared__ float ls[4], lss[4];
  const int wid = threadIdx.x >> 6, lane = threadIdx.x & 63;
  if (lane == 0) { ls[wid] = s; lss[wid] = ss; }
  __syncthreads();
  if (threadIdx.x == 0) {
    atomAddF(&stats[b*2+0], ls[0]+ls[1]+ls[2]+ls[3]);
    atomAddF(&stats[b*2+1], lss[0]+lss[1]+lss[2]+lss[3]);
  }
}

// ---------- 2. fold LN into 1x1 weights -> bf16 preswz (key o&7) ----------
__global__ void k_fold(const float* __restrict__ w_in, const float* __restrict__ ln_w,
                       const float* __restrict__ ln_b, const float* __restrict__ stats,
                       u16* __restrict__ W, float* __restrict__ bias, int O_real) {
  const int o = blockIdx.x, b = blockIdx.y, c = threadIdx.x;
  const int Mtot = gridDim.x;
  const float n = (float)(CDIM * NPIX);
  const float sum = stats[b*2], sumsq = stats[b*2+1];
  const float mean = sum / n;
  const float var = (sumsq - sum * sum / n) / (n - 1.f);
  const float inv = 1.f / (sqrtf(var) + 1e-6f);
  float we = 0.f, cb = 0.f;
  if (o < O_real) {
    float wi = w_in[o * CDIM + c];
    float a  = ln_w[c] * inv;
    we = wi * a;
    cb = wi * (ln_b[c] - mean * a);
  }
  int sch = (c >> 3) ^ (o & 7);
  W[((size_t)b * Mtot + o) * CDIM + sch * 8 + (c & 7)] = f2bf(we);
  for (int off = 32; off; off >>= 1) cb += __shfl_down(cb, off);
  __shared__ float l[3];
  if ((threadIdx.x & 63) == 0) l[threadIdx.x >> 6] = cb;
  __syncthreads();
  if (threadIdx.x == 0) bias[b * Mtot + o] = l[0] + l[1] + l[2];
}

// ---------- 2b. ff_out weights -> bf16 [192][512] preswz ----------
__global__ void k_fold3(const float* __restrict__ w, u16* __restrict__ W3) {
  const int o = blockIdx.x;
  for (int it = 0; it < 2; ++it) {
    int c = it * 256 + threadIdx.x;
    float v = (c < HIDN) ? w[o * HIDN + c] : 0.f;
    int sch = (c >> 3) ^ (o & 7);
    W3[o * 512 + sch * 8 + (c & 7)] = f2bf(v);
  }
}

// ---------- 3. transpose f32 planar [b][192][n] -> bf16 T [b][n][192] preswz ----------
__global__ __launch_bounds__(256) void k_tr(const float* __restrict__ P, u16* __restrict__ T) {
  __shared__ u16 ld[128][200];
  const int b = blockIdx.y, n0 = blockIdx.x * 128, tid = threadIdx.x;
  const float* Pb = P + (((size_t)b * CDIM) << 16) + n0;
  for (int it = 0; it < 96; ++it) {
    int idx = it * 256 + tid;
    int nl = idx & 127, c = idx >> 7;
    ld[nl][c] = f2bf(Pb[((size_t)c << 16) + nl]);
  }
  __syncthreads();
  u16* Tb = T + (size_t)(b * NPIX + n0) * CDIM;
  for (int it = 0; it < 12; ++it) {
    int idx = it * 256 + tid;
    int ch = idx % 24, nl = idx / 24;
    union { u16 s[8]; uint4 v; } t;
    #pragma unroll
    for (int r = 0; r < 8; ++r) t.s[r] = ld[nl][ch * 8 + r];
    int sch = ch ^ (nl & 7);
    *(uint4*)((char*)(Tb + (size_t)nl * CDIM) + sch * 16) = t.v;
  }
}

// ---------- 4. MFMA GEMM: out[b,o,n] = sum_c A[b,o,c]*B[b,n,c] ----------
// A,B bf16 preswz (A key o&7, B key n&7). Tile 64(o) x 128(n), 4 waves.
// EPI=0: bf16 planar out + bias. EPI=1: f32 out = acc + resid (in-place ok).
// STATS=1 (with EPI=1): accumulate sum/sumsq of results into stats[b*2..].
template <int KTOT, int KC, int EPI, int STATS>
__global__ __launch_bounds__(256) void k_mgemm(
    const u16* __restrict__ Bm, const u16* __restrict__ Am,
    const float* __restrict__ bias, const float* __restrict__ resid,
    void* __restrict__ outv, int Mtot,
    long Bbstr, long Abstr, long Obstr, int out_nstr,
    int nB_base, int nB_rows, int nO_base, float* __restrict__ stats)
{
  constexpr int RBC = KC * 2;
  __shared__ u16 lB[128 * KC];
  __shared__ u16 lA[64 * KC];
  const int b = blockIdx.z;
  const int o0 = blockIdx.x * 64;
  const int nB = nB_base + blockIdx.y * 128;
  const int nO = nO_base + blockIdx.y * 128;
  const int tid = threadIdx.x;
  const int lane = tid & 63;
  const int wid = tid >> 6;

  if (EPI == 0 && (nB < 0 || nB >= nB_rows)) {     // halo block outside image: zeros
    u16* op = (u16*)outv;
    uint4 z; z.x = z.y = z.z = z.w = 0u;
    for (int it = 0; it < 4; ++it) {
      int idx = it * 256 + tid;
      int orow = idx >> 4, c8 = idx & 15;
      *(uint4*)(op + (size_t)b * Obstr + (size_t)(o0 + orow) * out_nstr + nO + c8 * 8) = z;
    }
    return;
  }

  const u16* Bb = Bm + (size_t)b * Bbstr + (size_t)nB * KTOT;
  const u16* Ab = Am + (size_t)b * Abstr + (size_t)o0 * KTOT;

  f32x4 acc[4][2];
  #pragma unroll
  for (int m = 0; m < 4; ++m)
    #pragma unroll
    for (int nf = 0; nf < 2; ++nf) acc[m][nf] = (f32x4){0.f, 0.f, 0.f, 0.f};

  for (int kc0 = 0; kc0 < KTOT; kc0 += KC) {
    if (kc0) __syncthreads();
    if constexpr (KTOT == KC) {       // full rows: pure linear copy
      #pragma unroll
      for (int it = 0; it < 128 * RBC / 16 / 256; ++it) {
        int idx = it * 256 + tid;
        gload16((const char*)Bb + idx * 16, (char*)lB + idx * 16);
      }
      #pragma unroll
      for (int it = 0; it < 64 * RBC / 16 / 256; ++it) {
        int idx = it * 256 + tid;
        gload16((const char*)Ab + idx * 16, (char*)lA + idx * 16);
      }
    } else {                          // row segments
      constexpr int NCH = KC / 8;
      #pragma unroll
      for (int it = 0; it < 128 * NCH / 256; ++it) {
        int idx = it * 256 + tid; int r = idx / NCH, ch = idx % NCH;
        gload16((const char*)(Bb + (size_t)r * KTOT + kc0) + ch * 16, (char*)lB + idx * 16);
      }
      #pragma unroll
      for (int it = 0; it < 64 * NCH / 256; ++it) {
        int idx = it * 256 + tid; int r = idx / NCH, ch = idx % NCH;
        gload16((const char*)(Ab + (size_t)r * KTOT + kc0) + ch * 16, (char*)lA + idx * 16);
      }
    }
    __syncthreads();
    const int lr = lane & 15, g = lane >> 4;
    #pragma unroll
    for (int ks = 0; ks < KC / 32; ++ks) {
      const int ck = ks * 4 + g;
      short8 afr[4], bfr[2];
      #pragma unroll
      for (int m = 0; m < 4; ++m) {
        int row = m * 16 + lr;
        afr[m] = *(const short8*)((const char*)lA + row * RBC + ((ck ^ (row & 7)) << 4));
      }
      #pragma unroll
      for (int nf = 0; nf < 2; ++nf) {
        int row = wid * 32 + nf * 16 + lr;
        bfr[nf] = *(const short8*)((const char*)lB + row * RBC + ((ck ^ (row & 7)) << 4));
      }
      #pragma unroll
      for (int m = 0; m < 4; ++m)
        #pragma unroll
        for (int nf = 0; nf < 2; ++nf)
          acc[m][nf] = __builtin_amdgcn_mfma_f32_16x16x32_bf16(afr[m], bfr[nf], acc[m][nf], 0, 0, 0);
    }
  }

  const int col = lane & 15, rg = lane >> 4;
  if (EPI == 0) {
    u16* op = (u16*)outv;
    #pragma unroll
    for (int m = 0; m < 4; ++m)
      #pragma unroll
      for (int j = 0; j < 4; ++j) {
        int o = o0 + m * 16 + rg * 4 + j;
        float bv = bias[b * Mtot + o];
        #pragma unroll
        for (int nf = 0; nf < 2; ++nf) {
          int nn = nO + wid * 32 + nf * 16 + col;
          op[(size_t)b * Obstr + (size_t)o * out_nstr + nn] = f2bf(acc[m][nf][j] + bv);
        }
      }
  } else {
    float* of = (float*)outv;
    float s = 0.f, ss = 0.f;
    #pragma unroll
    for (int m = 0; m < 4; ++m)
      #pragma unroll
      for (int nf = 0; nf < 2; ++nf)
        #pragma unroll
        for (int j = 0; j < 4; ++j) {
          int o = o0 + m * 16 + rg * 4 + j;
          int nn = nO + wid * 32 + nf * 16 + col;
          size_t ix = (size_t)b * Obstr + (size_t)o * out_nstr + nn;
          float r = acc[m][nf][j] + resid[ix];
          of[ix] = r;
          if constexpr (STATS) { s += r; ss += r * r; }
        }
    if constexpr (STATS) {
      for (int off = 32; off; off >>= 1) { s += __shfl_down(s, off); ss += __shfl_down(ss, off); }
      __shared__ float sr1[4], sr2[4];
      if (lane == 0) { sr1[wid] = s; sr2[wid] = ss; }
      __syncthreads();
      if (tid == 0) {
        atomAddF(&stats[b*2+0], sr1[0]+sr1[1]+sr1[2]+sr1[3]);
        atomAddF(&stats[b*2+1], sr2[0]+sr2[1]+sr2[2]+sr2[3]);
      }
    }
  }
}

// ---------- 5. fused dw + Gram + L2 norms, one row strip per block ----------
__global__ __launch_bounds__(256) void k_gram_f(const u16* __restrict__ qkv,
                                                const float* __restrict__ dww,
                                                float* __restrict__ G,
                                                float* __restrict__ nq,
                                                float* __restrict__ nk) {
  __shared__ u16 qs[HD][260], ks[HD][260];
  __shared__ float wq[HD][9], wk[HD][9];
  const int b = blockIdx.y >> 2, h = blockIdx.y & 3;
  const int row = blockIdx.x;
  const int tid = threadIdx.x;

  for (int idx = tid; idx < HD * 9; idx += 256) {
    int c = idx / 9, k9 = idx % 9;
    wq[c][k9] = dww[(h * HD + c) * 9 + k9];
    wk[c][k9] = dww[(CDIM + h * HD + c) * 9 + k9];
  }
  __syncthreads();

  for (int idx = tid; idx < HD * 256; idx += 256) {
    const int c = idx >> 8, col = idx & 255;
    const u16* qb = qkv + (((size_t)(b * OQKV + h * HD + c)) << 16);
    const u16* kb = qkv + (((size_t)(b * OQKV + CDIM + h * HD + c)) << 16);
    float aq = 0.f, ak = 0.f;
    #pragma unroll
    for (int dr = -1; dr <= 1; ++dr) {
      int rr = row + dr; if (rr < 0 || rr > 255) continue;
      #pragma unroll
      for (int dc = -1; dc <= 1; ++dc) {
        int cc = col + dc; if (cc < 0 || cc > 255) continue;
        float wq9 = wq[c][(dr+1)*3 + dc+1], wk9 = wk[c][(dr+1)*3 + dc+1];
        aq += wq9 * bf2f(qb[rr * 256 + cc]);
        ak += wk9 * bf2f(kb[rr * 256 + cc]);
      }
    }
    qs[c][col] = f2bf(aq); ks[c][col] = f2bf(ak);
  }
  __syncthreads();

  const int tc = tid & 15, td = tid >> 4;
  float g[3][3] = {};
  float sq[3] = {}, sk[3] = {};
  for (int n = 0; n < 256; ++n) {
    float qv[3], kv[3];
    #pragma unroll
    for (int i = 0; i < 3; ++i) { qv[i] = bf2f(qs[tc*3+i][n]); kv[i] = bf2f(ks[td*3+i][n]); }
    #pragma unroll
    for (int i = 0; i < 3; ++i)
      #pragma unroll
      for (int j = 0; j < 3; ++j) g[i][j] += qv[i] * kv[j];
    if (td == 0) { sq[0] += qv[0]*qv[0]; sq[1] += qv[1]*qv[1]; sq[2] += qv[2]*qv[2]; }
    if (tc == 0) { sk[0] += kv[0]*kv[0]; sk[1] += kv[1]*kv[1]; sk[2] += kv[2]*kv[2]; }
  }
  float* Gb = G + (size_t)(b * NHEADS + h) * HD * HD;
  #pragma unroll
  for (int i = 0; i < 3; ++i)
    #pragma unroll
    for (int j = 0; j < 3; ++j) atomAddF(&Gb[(tc*3+i) * HD + td*3+j], g[i][j]);
  if (td == 0) { for (int i = 0; i < 3; ++i) atomAddF(&nq[(b*NHEADS+h)*HD + tc*3+i], sq[i]); }
  if (tc == 0) { for (int i = 0; i < 3; ++i) atomAddF(&nk[(b*NHEADS+h)*HD + td*3+i], sk[i]); }
}

// ---------- 6. normalize, softmax, combine with proj -> M bf16 preswz [b,192,192] ----------
__global__ void k_attnM(const float* __restrict__ G, const float* __restrict__ nq,
                        const float* __restrict__ nk, const float* __restrict__ temp,
                        const float* __restrict__ proj_w, u16* __restrict__ Mb16) {
  const int h = blockIdx.x, b = blockIdx.y;
  __shared__ float at[HD][HD];
  const float* Gb = G + (size_t)(b * NHEADS + h) * HD * HD;
  const float* nqb = nq + (b * NHEADS + h) * HD;
  const float* nkb = nk + (b * NHEADS + h) * HD;
  const float t = temp[h];
  const int tid = threadIdx.x;
  for (int idx = tid; idx < HD * HD; idx += 256) {
    int c = idx / HD, d = idx % HD;
    float qn = fmaxf(sqrtf(nqb[c]), 1e-12f);
    float kn = fmaxf(sqrtf(nkb[d]), 1e-12f);
    at[c][d] = Gb[idx] / (qn * kn) * t;
  }
  __syncthreads();
  if (tid < HD) {
    float m = -1e30f;
    for (int d = 0; d < HD; ++d) m = fmaxf(m, at[tid][d]);
    float s = 0.f;
    for (int d = 0; d < HD; ++d) { float e = __expf(at[tid][d] - m); at[tid][d] = e; s += e; }
    float inv = 1.f / s;
    for (int d = 0; d < HD; ++d) at[tid][d] *= inv;
  }
  __syncthreads();
  for (int idx = tid; idx < CDIM * HD; idx += 256) {
    int o = idx / HD, d = idx % HD;
    float acc = 0.f;
    for (int c = 0; c < HD; ++c) acc += proj_w[o * CDIM + h * HD + c] * at[c][d];
    int cf = h * HD + d;
    int sch = (cf >> 3) ^ (o & 7);
    Mb16[((size_t)(b * CDIM + o)) * CDIM + sch * 8 + (cf & 7)] = f2bf(acc);
  }
}

// ---------- 7. dw conv on V -> transposed preswz bf16 [b][n][192] ----------
__global__ __launch_bounds__(256) void k_dwT(const u16* __restrict__ qkv,
                                             const float* __restrict__ dww,
                                             u16* __restrict__ vdwT) {
  __shared__ u16 ld[64][200];
  __shared__ float w9[CDIM][9];
  const int b = blockIdx.y;
  const int p0 = blockIdx.x * 64;
  const int row = p0 >> 8, col0 = p0 & 255;
  const int tid = threadIdx.x;
  for (int idx = tid; idx < CDIM * 9; idx += 256) w9[idx / 9][idx % 9] = dww[384 * 9 + idx];
  __syncthreads();
  for (int it = 0; it < 48; ++it) {
    int idx = it * 256 + tid;
    int c = idx >> 6, px = idx & 63;
    const u16* vb = qkv + (((size_t)(b * OQKV + 384 + c)) << 16);
    int col = col0 + px;
    float a = 0.f;
    #pragma unroll
    for (int dr = -1; dr <= 1; ++dr) {
      int rr = row + dr; if (rr < 0 || rr > 255) continue;
      #pragma unroll
      for (int dc = -1; dc <= 1; ++dc) {
        int cc = col + dc; if (cc < 0 || cc > 255) continue;
        a += w9[c][(dr+1)*3 + dc+1] * bf2f(vb[rr * 256 + cc]);
      }
    }
    ld[px][c] = f2bf(a);
  }
  __syncthreads();
  u16* Tb = vdwT + ((size_t)(b * NPIX + p0)) * CDIM;
  for (int it = 0; it < 6; ++it) {
    int idx = it * 256 + tid;         // 1536 = 64 px * 24 chunks
    int ch = idx % 24, pl = idx / 24;
    union { u16 s[8]; uint4 v; } t;
    #pragma unroll
    for (int r = 0; r < 8; ++r) t.s[r] = ld[pl][ch * 8 + r];
    int sch = ch ^ (pl & 7);
    *(uint4*)((char*)(Tb + (size_t)pl * CDIM) + sch * 16) = t.v;
  }
}

// ---------- 8. dw + gelu gate on hpre band -> ygT bf16 [b][band_px][512] preswz ----------
__global__ __launch_bounds__(256) void k_dwgT(const u16* __restrict__ hp_, const float* __restrict__ w9,
                                              u16* __restrict__ ygT, int rows_loc, int band_px) {
  __shared__ u16 ld[64][520];
  const int b = blockIdx.y;
  const int p0 = blockIdx.x * 64;
  const int olr = p0 >> 8, col0 = p0 & 255;
  const int tid = threadIdx.x;
  for (int it = 0; it < 128; ++it) {
    int idx = it * 256 + tid;
    int c = idx >> 6, px = idx & 63;
    float v = 0.f;
    if (c < HIDN) {
      const u16* ia = hp_ + (size_t)(b * OPAD + c) * rows_loc * 256;
      const u16* ig = hp_ + (size_t)(b * OPAD + c + HIDN) * rows_loc * 256;
      float a = 0.f, g = 0.f;
      #pragma unroll
      for (int dr = 0; dr < 3; ++dr) {
        #pragma unroll
        for (int dc = -1; dc <= 1; ++dc) {
          int cc = col0 + px + dc;
          if (cc < 0 || cc > 255) continue;
          float wa = w9[c * 9 + dr * 3 + dc + 1];
          float wg = w9[(c + HIDN) * 9 + dr * 3 + dc + 1];
          a += wa * bf2f(ia[(olr + dr) * 256 + cc]);
          g += wg * bf2f(ig[(olr + dr) * 256 + cc]);
        }
      }
      float gel = 0.5f * a * (1.f + erff(a * 0.70710678118654752f));
      v = gel * g;
    }
    ld[px][c] = f2bf(v);
  }
  __syncthreads();
  u16* Tb = ygT + ((size_t)b * band_px + p0) * 512;
  for (int it = 0; it < 16; ++it) {
    int idx = it * 256 + tid;
    int ch = idx & 63, pl = idx >> 6;
    union { u16 s[8]; uint4 v; } t;
    #pragma unroll
    for (int r = 0; r < 8; ++r) t.s[r] = ld[pl][ch * 8 + r];
    int sch = ch ^ (pl & 7);
    *(uint4*)((char*)(Tb + (size_t)pl * 512) + sch * 16) = t.v;
  }
}

// ---------- launch ----------
extern "C" void kernel_launch(void* const* d_in, const int* in_sizes, int n_in,
                              void* d_out, int out_size, void* d_ws, size_t ws_size,
                              hipStream_t stream) {
  const float* x       = (const float*)d_in[0];
  const float* n1_w    = (const float*)d_in[1];
  const float* n1_b    = (const float*)d_in[2];
  const float* qkv_w   = (const float*)d_in[3];
  const float* qkv_dw  = (const float*)d_in[4];
  const float* proj_w  = (const float*)d_in[5];
  const float* temp    = (const float*)d_in[6];
  const float* n2_w    = (const float*)d_in[7];
  const float* n2_b    = (const float*)d_in[8];
  const float* ff_in_w = (const float*)d_in[9];
  const float* ff_dw   = (const float*)d_in[10];
  const float* ff_out_w= (const float*)d_in[11];

  char* ws = (char*)d_ws;
  float* stats1 = (float*)(ws + OFF_STATS1);
  float* stats2 = (float*)(ws + OFF_STATS2);
  float* G      = (float*)(ws + OFF_G);
  float* nq     = (float*)(ws + OFF_NQ);
  float* nk     = (float*)(ws + OFF_NK);
  float* biasq  = (float*)(ws + OFF_BQ);
  float* bias2  = (float*)(ws + OFF_B2);
  u16*   Mb16   = (u16*)(ws + OFF_M);
  u16*   Wq     = (u16*)(ws + OFF_WQ);
  u16*   W2b    = (u16*)(ws + OFF_W2B);
  u16*   W3     = (u16*)(ws + OFF_W3);
  u16*   xT     = (u16*)(ws + OFF_T);      // xT -> vdwT -> x2T
  u16*   qkv    = (u16*)(ws + OFF_QKV);
  float* outp   = (float*)d_out;

  // pick GDFN band count from available workspace (+8MB safety margin)
  int NP = 32;
  const int cand[4] = {2, 4, 8, 16};
  for (int i = 0; i < 4; ++i) {
    int rws = 256 / cand[i], rl = rws + 2;
    size_t band = (size_t)2 * OPAD * rl * 256 * 2 + (size_t)2 * rws * 256 * 512 * 2;
    if (OFF_BAND + band + ((size_t)8 << 20) <= ws_size) { NP = cand[i]; break; }
  }
  const int rows = 256 / NP, rows_loc = rows + 2, band_px = rows * 256;
  u16* hpre = (u16*)(ws + OFF_BAND);
  u16* ygT  = (u16*)(ws + OFF_BAND + (size_t)2 * OPAD * rows_loc * 256 * 2);

  hipMemsetAsync(ws, 0, ZERO_BYTES, stream);

  // ---- attention ----
  k_stats<<<dim3(1024, BATCH), 256, 0, stream>>>(x, stats1);
  k_fold<<<dim3(OQKV, BATCH), CDIM, 0, stream>>>(qkv_w, n1_w, n1_b, stats1, Wq, biasq, OQKV);
  k_tr<<<dim3(NPIX / 128, BATCH), 256, 0, stream>>>(x, xT);
  k_mgemm<192, 192, 0, 0><<<dim3(OQKV / 64, NPIX / 128, BATCH), 256, 0, stream>>>(
      xT, Wq, biasq, nullptr, qkv, OQKV,
      (long)NPIX * CDIM, (long)OQKV * CDIM, (long)OQKV * NPIX, NPIX, 0, NPIX, 0, nullptr);
  k_gram_f<<<dim3(256, BATCH * NHEADS), 256, 0, stream>>>(qkv, qkv_dw, G, nq, nk);
  k_attnM<<<dim3(NHEADS, BATCH), 256, 0, stream>>>(G, nq, nk, temp, proj_w, Mb16);
  k_dwT<<<dim3(NPIX / 64, BATCH), 256, 0, stream>>>(qkv, qkv_dw, xT);   // vdwT over xT
  k_mgemm<192, 192, 1, 1><<<dim3(CDIM / 64, NPIX / 128, BATCH), 256, 0, stream>>>(
      xT, Mb16, nullptr, x, outp, CDIM,
      (long)NPIX * CDIM, (long)CDIM * CDIM, (long)CDIM * NPIX, NPIX, 0, NPIX, 0, stats2);

  // ---- GDFN ----
  k_tr<<<dim3(NPIX / 128, BATCH), 256, 0, stream>>>(outp, xT);   // x2T (reuse region)
  k_fold<<<dim3(OPAD, BATCH), CDIM, 0, stream>>>(ff_in_w, n2_w, n2_b, stats2, W2b, bias2, 1020);
  k_fold3<<<dim3(CDIM), 256, 0, stream>>>(ff_out_w, W3);
  for (int rp = 0; rp < NP; ++rp) {
    const int band0 = rp * band_px;
    k_mgemm<192, 192, 0, 0><<<dim3(OPAD / 64, rows_loc * 2, BATCH), 256, 0, stream>>>(
        xT, W2b, bias2, nullptr, hpre, OPAD,
        (long)NPIX * CDIM, (long)OPAD * CDIM, (long)OPAD * rows_loc * 256, rows_loc * 256,
        band0 - 256, NPIX, 0, nullptr);
    k_dwgT<<<dim3(band_px / 64, BATCH), 256, 0, stream>>>(hpre, ff_dw, ygT, rows_loc, band_px);
    k_mgemm<512, 256, 1, 0><<<dim3(CDIM / 64, rows * 2, BATCH), 256, 0, stream>>>(
        ygT, W3, nullptr, outp, outp, CDIM,
        (long)band_px * 512, 0L, (long)CDIM * NPIX, NPIX, 0, band_px, band0, nullptr);
  }
}

// Round 5
// 1138.881 us; speedup vs baseline: 3.5675x; 2.2752x over previous
//
#include <hip/hip_runtime.h>
#include <hip/hip_bf16.h>

typedef unsigned short u16;
typedef __attribute__((ext_vector_type(8))) short short8;
typedef __attribute__((ext_vector_type(8))) unsigned short ushort8v;
typedef __attribute__((ext_vector_type(4))) float f32x4;

#define NPIX  65536
#define HH    256
#define WW    256
#define BATCH 2
#define CDIM  192
#define NHEADS 4
#define HD    48
#define OQKV  576
#define HIDN  510
#define OPAD  1024

// ---------- helpers ----------
__device__ __forceinline__ float bf2f(u16 b) {
  union { unsigned u; float f; } v; v.u = ((unsigned)b) << 16; return v.f;
}
__device__ __forceinline__ u16 f2bf(float f) {
  union { float f; unsigned u; } v; v.f = f;
  unsigned r = v.u + 0x7fffu + ((v.u >> 16) & 1u);
  return (u16)(r >> 16);
}
__device__ __forceinline__ void atomAddF(float* p, float v) { unsafeAtomicAdd(p, v); }
__device__ __forceinline__ void gload16(const void* g, void* l) {
  __builtin_amdgcn_global_load_lds((const __attribute__((address_space(1))) unsigned int*)g,
                                   (__attribute__((address_space(3))) unsigned int*)l, 16, 0, 0);
}
// 3-tap row conv on 8 consecutive px starting at col jm (row base rp). 1 vec + 2 scalar loads.
__device__ __forceinline__ void dw3row(const u16* __restrict__ rp, int jm, bool hasL, bool hasR,
                                       float w0, float w1, float w2, float* acc) {
  ushort8v m = *(const ushort8v*)(rp + jm);
  float f[10];
  f[0] = hasL ? bf2f(rp[jm - 1]) : 0.f;
  #pragma unroll
  for (int t = 0; t < 8; ++t) f[t + 1] = bf2f(m[t]);
  f[9] = hasR ? bf2f(rp[jm + 8]) : 0.f;
  #pragma unroll
  for (int i = 0; i < 8; ++i) acc[i] += w0 * f[i] + w1 * f[i + 1] + w2 * f[i + 2];
}

// ---------- ws layout (bytes) ----------
#define OFF_STATS1 ((size_t)0)
#define OFF_STATS2 ((size_t)64)
#define OFF_G      ((size_t)128)                  // 2*4*48*48*4 = 73728
#define OFF_NQ     (OFF_G + 73728)
#define OFF_NK     (OFF_NQ + 1536)
#define ZERO_BYTES (OFF_NK + 1536)                // 76928, zeroed each launch
#define OFF_BQ     ((size_t)77056)                // f32 [2][576]
#define OFF_B2     (OFF_BQ + 4608)                // f32 [2][1024]
#define OFF_M      (OFF_B2 + 8192)                // bf16 preswz [2][192][192] (reserved 294912)
#define OFF_WQ     (OFF_M + 294912)               // bf16 [2][576][192] preswz
#define OFF_W2B    (OFF_WQ + 442368)              // bf16 [2][1024][192] preswz
#define OFF_W3     (OFF_W2B + 786432)             // bf16 [192][512] preswz
#define OFF_T      (OFF_W3 + 196608)              // bf16 T [2][65536][192]: xT -> vdwT -> x2T
#define OFF_QKV    (OFF_T + 50331648)             // bf16 planar [2][576][65536]
#define OFF_BAND   (OFF_QKV + 150994944)          // hpre band + ygT band

// ---------- 1. global LN stats ----------
__global__ void k_stats(const float* __restrict__ x, float* __restrict__ stats) {
  const int b = blockIdx.y;
  const float4* xb = (const float4*)(x + (size_t)b * CDIM * NPIX);
  const int n4 = CDIM * NPIX / 4;
  float s = 0.f, ss = 0.f;
  for (int i = blockIdx.x * blockDim.x + threadIdx.x; i < n4; i += gridDim.x * blockDim.x) {
    float4 v = xb[i];
    s  += v.x + v.y + v.z + v.w;
    ss += v.x*v.x + v.y*v.y + v.z*v.z + v.w*v.w;
  }
  for (int off = 32; off; off >>= 1) { s += __shfl_down(s, off); ss += __shfl_down(ss, off); }
  __shared__ float ls[4], lss[4];
  const int wid = threadIdx.x >> 6, lane = threadIdx.x & 63;
  if (lane == 0) { ls[wid] = s; lss[wid] = ss; }
  __syncthreads();
  if (threadIdx.x == 0) {
    atomAddF(&stats[b*2+0], ls[0]+ls[1]+ls[2]+ls[3]);
    atomAddF(&stats[b*2+1], lss[0]+lss[1]+lss[2]+lss[3]);
  }
}

// ---------- 2. fold LN into 1x1 weights -> bf16 preswz (key o&7) ----------
__global__ void k_fold(const float* __restrict__ w_in, const float* __restrict__ ln_w,
                       const float* __restrict__ ln_b, const float* __restrict__ stats,
                       u16* __restrict__ W, float* __restrict__ bias, int O_real) {
  const int o = blockIdx.x, b = blockIdx.y, c = threadIdx.x;
  const int Mtot = gridDim.x;
  const float n = (float)(CDIM * NPIX);
  const float sum = stats[b*2], sumsq = stats[b*2+1];
  const float mean = sum / n;
  const float var = (sumsq - sum * sum / n) / (n - 1.f);
  const float inv = 1.f / (sqrtf(var) + 1e-6f);
  float we = 0.f, cb = 0.f;
  if (o < O_real) {
    float wi = w_in[o * CDIM + c];
    float a  = ln_w[c] * inv;
    we = wi * a;
    cb = wi * (ln_b[c] - mean * a);
  }
  int sch = (c >> 3) ^ (o & 7);
  W[((size_t)b * Mtot + o) * CDIM + sch * 8 + (c & 7)] = f2bf(we);
  for (int off = 32; off; off >>= 1) cb += __shfl_down(cb, off);
  __shared__ float l[3];
  if ((threadIdx.x & 63) == 0) l[threadIdx.x >> 6] = cb;
  __syncthreads();
  if (threadIdx.x == 0) bias[b * Mtot + o] = l[0] + l[1] + l[2];
}

// ---------- 2b. ff_out weights -> bf16 [192][512] preswz ----------
__global__ void k_fold3(const float* __restrict__ w, u16* __restrict__ W3) {
  const int o = blockIdx.x;
  for (int it = 0; it < 2; ++it) {
    int c = it * 256 + threadIdx.x;
    float v = (c < HIDN) ? w[o * HIDN + c] : 0.f;
    int sch = (c >> 3) ^ (o & 7);
    W3[o * 512 + sch * 8 + (c & 7)] = f2bf(v);
  }
}

// ---------- 3. transpose f32 planar [b][192][n] -> bf16 T [b][n][192] preswz ----------
__global__ __launch_bounds__(256) void k_tr(const float* __restrict__ P, u16* __restrict__ T) {
  __shared__ u16 ld[128][200];
  const int b = blockIdx.y, n0 = blockIdx.x * 128, tid = threadIdx.x;
  const float* Pb = P + (((size_t)b * CDIM) << 16) + n0;
  for (int it = 0; it < 96; ++it) {
    int idx = it * 256 + tid;
    int nl = idx & 127, c = idx >> 7;
    ld[nl][c] = f2bf(Pb[((size_t)c << 16) + nl]);
  }
  __syncthreads();
  u16* Tb = T + (size_t)(b * NPIX + n0) * CDIM;
  for (int it = 0; it < 12; ++it) {
    int idx = it * 256 + tid;
    int ch = idx % 24, nl = idx / 24;
    union { u16 s[8]; uint4 v; } t;
    #pragma unroll
    for (int r = 0; r < 8; ++r) t.s[r] = ld[nl][ch * 8 + r];
    int sch = ch ^ (nl & 7);
    *(uint4*)((char*)(Tb + (size_t)nl * CDIM) + sch * 16) = t.v;
  }
}

// ---------- 4. MFMA GEMM: out[b,o,n] = sum_c A[b,o,c]*B[b,n,c] ----------
template <int KTOT, int KC, int EPI, int STATS>
__global__ __launch_bounds__(256) void k_mgemm(
    const u16* __restrict__ Bm, const u16* __restrict__ Am,
    const float* __restrict__ bias, const float* __restrict__ resid,
    void* __restrict__ outv, int Mtot,
    long Bbstr, long Abstr, long Obstr, int out_nstr,
    int nB_base, int nB_rows, int nO_base, float* __restrict__ stats)
{
  constexpr int RBC = KC * 2;
  __shared__ u16 lB[128 * KC];
  __shared__ u16 lA[64 * KC];
  const int b = blockIdx.z;
  const int o0 = blockIdx.x * 64;
  const int nB = nB_base + blockIdx.y * 128;
  const int nO = nO_base + blockIdx.y * 128;
  const int tid = threadIdx.x;
  const int lane = tid & 63;
  const int wid = tid >> 6;

  if (EPI == 0 && (nB < 0 || nB >= nB_rows)) {
    u16* op = (u16*)outv;
    uint4 z; z.x = z.y = z.z = z.w = 0u;
    for (int it = 0; it < 4; ++it) {
      int idx = it * 256 + tid;
      int orow = idx >> 4, c8 = idx & 15;
      *(uint4*)(op + (size_t)b * Obstr + (size_t)(o0 + orow) * out_nstr + nO + c8 * 8) = z;
    }
    return;
  }

  const u16* Bb = Bm + (size_t)b * Bbstr + (size_t)nB * KTOT;
  const u16* Ab = Am + (size_t)b * Abstr + (size_t)o0 * KTOT;

  f32x4 acc[4][2];
  #pragma unroll
  for (int m = 0; m < 4; ++m)
    #pragma unroll
    for (int nf = 0; nf < 2; ++nf) acc[m][nf] = (f32x4){0.f, 0.f, 0.f, 0.f};

  for (int kc0 = 0; kc0 < KTOT; kc0 += KC) {
    if (kc0) __syncthreads();
    if constexpr (KTOT == KC) {
      #pragma unroll
      for (int it = 0; it < 128 * RBC / 16 / 256; ++it) {
        int idx = it * 256 + tid;
        gload16((const char*)Bb + idx * 16, (char*)lB + idx * 16);
      }
      #pragma unroll
      for (int it = 0; it < 64 * RBC / 16 / 256; ++it) {
        int idx = it * 256 + tid;
        gload16((const char*)Ab + idx * 16, (char*)lA + idx * 16);
      }
    } else {
      constexpr int NCH = KC / 8;
      #pragma unroll
      for (int it = 0; it < 128 * NCH / 256; ++it) {
        int idx = it * 256 + tid; int r = idx / NCH, ch = idx % NCH;
        gload16((const char*)(Bb + (size_t)r * KTOT + kc0) + ch * 16, (char*)lB + idx * 16);
      }
      #pragma unroll
      for (int it = 0; it < 64 * NCH / 256; ++it) {
        int idx = it * 256 + tid; int r = idx / NCH, ch = idx % NCH;
        gload16((const char*)(Ab + (size_t)r * KTOT + kc0) + ch * 16, (char*)lA + idx * 16);
      }
    }
    __syncthreads();
    const int lr = lane & 15, g = lane >> 4;
    #pragma unroll
    for (int ks = 0; ks < KC / 32; ++ks) {
      const int ck = ks * 4 + g;
      short8 afr[4], bfr[2];
      #pragma unroll
      for (int m = 0; m < 4; ++m) {
        int row = m * 16 + lr;
        afr[m] = *(const short8*)((const char*)lA + row * RBC + ((ck ^ (row & 7)) << 4));
      }
      #pragma unroll
      for (int nf = 0; nf < 2; ++nf) {
        int row = wid * 32 + nf * 16 + lr;
        bfr[nf] = *(const short8*)((const char*)lB + row * RBC + ((ck ^ (row & 7)) << 4));
      }
      #pragma unroll
      for (int m = 0; m < 4; ++m)
        #pragma unroll
        for (int nf = 0; nf < 2; ++nf)
          acc[m][nf] = __builtin_amdgcn_mfma_f32_16x16x32_bf16(afr[m], bfr[nf], acc[m][nf], 0, 0, 0);
    }
  }

  const int col = lane & 15, rg = lane >> 4;
  if (EPI == 0) {
    u16* op = (u16*)outv;
    #pragma unroll
    for (int m = 0; m < 4; ++m)
      #pragma unroll
      for (int j = 0; j < 4; ++j) {
        int o = o0 + m * 16 + rg * 4 + j;
        float bv = bias[b * Mtot + o];
        #pragma unroll
        for (int nf = 0; nf < 2; ++nf) {
          int nn = nO + wid * 32 + nf * 16 + col;
          op[(size_t)b * Obstr + (size_t)o * out_nstr + nn] = f2bf(acc[m][nf][j] + bv);
        }
      }
  } else {
    float* of = (float*)outv;
    float s = 0.f, ss = 0.f;
    #pragma unroll
    for (int m = 0; m < 4; ++m)
      #pragma unroll
      for (int nf = 0; nf < 2; ++nf)
        #pragma unroll
        for (int j = 0; j < 4; ++j) {
          int o = o0 + m * 16 + rg * 4 + j;
          int nn = nO + wid * 32 + nf * 16 + col;
          size_t ix = (size_t)b * Obstr + (size_t)o * out_nstr + nn;
          float r = acc[m][nf][j] + resid[ix];
          of[ix] = r;
          if constexpr (STATS) { s += r; ss += r * r; }
        }
    if constexpr (STATS) {
      for (int off = 32; off; off >>= 1) { s += __shfl_down(s, off); ss += __shfl_down(ss, off); }
      __shared__ float sr1[4], sr2[4];
      if (lane == 0) { sr1[wid] = s; sr2[wid] = ss; }
      __syncthreads();
      if (tid == 0) {
        atomAddF(&stats[b*2+0], sr1[0]+sr1[1]+sr1[2]+sr1[3]);
        atomAddF(&stats[b*2+1], sr2[0]+sr2[1]+sr2[2]+sr2[3]);
      }
    }
  }
}

// ---------- 5. fused dw + Gram(MFMA) + L2 norms, one row per block ----------
__global__ __launch_bounds__(256) void k_gram(const u16* __restrict__ qkv,
                                              const float* __restrict__ dww,
                                              float* __restrict__ G,
                                              float* __restrict__ nq,
                                              float* __restrict__ nk) {
  __shared__ u16 qs[HD][264], ks2[HD][264];
  __shared__ float wq[HD][9], wk[HD][9];
  __shared__ float nql[HD], nkl[HD];
  const int b = blockIdx.y >> 2, h = blockIdx.y & 3;
  const int row = blockIdx.x;
  const int tid = threadIdx.x;

  for (int idx = tid; idx < HD * 9; idx += 256) {
    int c = idx / 9, k9 = idx % 9;
    wq[c][k9] = dww[(h * HD + c) * 9 + k9];
    wk[c][k9] = dww[(CDIM + h * HD + c) * 9 + k9];
  }
  if (tid < HD) { nql[tid] = 0.f; nkl[tid] = 0.f; }
  __syncthreads();

  // phase 1: vectorized dw conv of q,k for this row into LDS (+ norm partials)
  for (int it = 0; it < 12; ++it) {
    int idx = it * 256 + tid;          // 3072 items: j(32) x c(48) x qk(2)
    int j = idx & 31, cz = idx >> 5;
    int c = cz % HD, qk = cz / HD;
    const u16* base = qkv + (((size_t)(b * OQKV + qk * CDIM + h * HD + c)) << 16);
    const float* w = qk ? wk[c] : wq[c];
    float acc[8] = {0.f,0.f,0.f,0.f,0.f,0.f,0.f,0.f};
    const int jm = j * 8;
    const bool hasL = j > 0, hasR = j < 31;
    if (row > 0)   dw3row(base + (row - 1) * 256, jm, hasL, hasR, w[0], w[1], w[2], acc);
                   dw3row(base + row * 256,       jm, hasL, hasR, w[3], w[4], w[5], acc);
    if (row < 255) dw3row(base + (row + 1) * 256, jm, hasL, hasR, w[6], w[7], w[8], acc);
    union { u16 s[8]; ushort8v v; } rv;
    float sqs = 0.f;
    #pragma unroll
    for (int i = 0; i < 8; ++i) {
      rv.s[i] = f2bf(acc[i]);
      float vv = bf2f(rv.s[i]);
      sqs += vv * vv;
    }
    if (qk) { *(ushort8v*)&ks2[c][jm] = rv.v; atomicAdd(&nkl[c], sqs); }
    else    { *(ushort8v*)&qs[c][jm]  = rv.v; atomicAdd(&nql[c], sqs); }
  }
  __syncthreads();

  // norms out (partials ready)
  if (tid < HD) atomAddF(&nq[(b*NHEADS+h)*HD + tid], nql[tid]);
  else if (tid < 2*HD) atomAddF(&nk[(b*NHEADS+h)*HD + tid - HD], nkl[tid - HD]);

  // phase 2: Gram via MFMA; 9 fragment tiles over 4 waves
  const int lane = tid & 63, wid = tid >> 6;
  const int lr = lane & 15, g = lane >> 4;
  float* Gb = G + (size_t)(b * NHEADS + h) * HD * HD;
  for (int t = wid; t < 9; t += 4) {
    const int m = t / 3, nb = t % 3;
    f32x4 a4 = (f32x4){0.f, 0.f, 0.f, 0.f};
    #pragma unroll
    for (int ksi = 0; ksi < 8; ++ksi) {
      int off = ksi * 32 + g * 8;
      short8 af = *(const short8*)&qs[m * 16 + lr][off];
      short8 bf = *(const short8*)&ks2[nb * 16 + lr][off];
      a4 = __builtin_amdgcn_mfma_f32_16x16x32_bf16(af, bf, a4, 0, 0, 0);
    }
    #pragma unroll
    for (int jj = 0; jj < 4; ++jj)
      atomAddF(&Gb[(m * 16 + g * 4 + jj) * HD + nb * 16 + lr], a4[jj]);
  }
}

// ---------- 6. normalize, softmax, combine with proj -> M bf16 preswz ----------
__global__ void k_attnM(const float* __restrict__ G, const float* __restrict__ nq,
                        const float* __restrict__ nk, const float* __restrict__ temp,
                        const float* __restrict__ proj_w, u16* __restrict__ Mb16) {
  const int h = blockIdx.x, b = blockIdx.y;
  __shared__ float at[HD][HD];
  const float* Gb = G + (size_t)(b * NHEADS + h) * HD * HD;
  const float* nqb = nq + (b * NHEADS + h) * HD;
  const float* nkb = nk + (b * NHEADS + h) * HD;
  const float t = temp[h];
  const int tid = threadIdx.x;
  for (int idx = tid; idx < HD * HD; idx += 256) {
    int c = idx / HD, d = idx % HD;
    float qn = fmaxf(sqrtf(nqb[c]), 1e-12f);
    float kn = fmaxf(sqrtf(nkb[d]), 1e-12f);
    at[c][d] = Gb[idx] / (qn * kn) * t;
  }
  __syncthreads();
  if (tid < HD) {
    float m = -1e30f;
    for (int d = 0; d < HD; ++d) m = fmaxf(m, at[tid][d]);
    float s = 0.f;
    for (int d = 0; d < HD; ++d) { float e = __expf(at[tid][d] - m); at[tid][d] = e; s += e; }
    float inv = 1.f / s;
    for (int d = 0; d < HD; ++d) at[tid][d] *= inv;
  }
  __syncthreads();
  for (int idx = tid; idx < CDIM * HD; idx += 256) {
    int o = idx / HD, d = idx % HD;
    float acc = 0.f;
    for (int c = 0; c < HD; ++c) acc += proj_w[o * CDIM + h * HD + c] * at[c][d];
    int cf = h * HD + d;
    int sch = (cf >> 3) ^ (o & 7);
    Mb16[((size_t)(b * CDIM + o)) * CDIM + sch * 8 + (cf & 7)] = f2bf(acc);
  }
}

// ---------- 7. dw conv on V -> transposed preswz bf16 [b][n][192] ----------
__global__ __launch_bounds__(256) void k_dwT(const u16* __restrict__ qkv,
                                             const float* __restrict__ dww,
                                             u16* __restrict__ vdwT) {
  __shared__ u16 ld[64][201];
  __shared__ float w9[CDIM][9];
  const int b = blockIdx.y;
  const int p0 = blockIdx.x * 64;
  const int row = p0 >> 8, col0 = p0 & 255;
  const int tid = threadIdx.x;
  for (int idx = tid; idx < CDIM * 9; idx += 256) w9[idx / 9][idx % 9] = dww[384 * 9 + idx];
  __syncthreads();
  for (int it = 0; it < 6; ++it) {
    int idx = it * 256 + tid;          // 1536 items: j(8) x c(192)
    int j = idx & 7, c = idx >> 3;
    const u16* base = qkv + (((size_t)(b * OQKV + 384 + c)) << 16);
    const float* w = w9[c];
    float acc[8] = {0.f,0.f,0.f,0.f,0.f,0.f,0.f,0.f};
    const int jm = col0 + j * 8;
    const bool hasL = jm > 0, hasR = jm < 248;
    if (row > 0)   dw3row(base + (row - 1) * 256, jm, hasL, hasR, w[0], w[1], w[2], acc);
                   dw3row(base + row * 256,       jm, hasL, hasR, w[3], w[4], w[5], acc);
    if (row < 255) dw3row(base + (row + 1) * 256, jm, hasL, hasR, w[6], w[7], w[8], acc);
    #pragma unroll
    for (int i = 0; i < 8; ++i) ld[j * 8 + i][c] = f2bf(acc[i]);
  }
  __syncthreads();
  u16* Tb = vdwT + ((size_t)(b * NPIX + p0)) * CDIM;
  for (int it = 0; it < 6; ++it) {
    int idx = it * 256 + tid;          // 1536 = 64 px * 24 chunks
    int ch = idx % 24, pl = idx / 24;
    union { u16 s[8]; uint4 v; } t;
    #pragma unroll
    for (int r = 0; r < 8; ++r) t.s[r] = ld[pl][ch * 8 + r];
    int sch = ch ^ (pl & 7);
    *(uint4*)((char*)(Tb + (size_t)pl * CDIM) + sch * 16) = t.v;
  }
}

// ---------- 8. dw + gelu gate on hpre band -> ygT bf16 [b][band_px][512] preswz ----------
__global__ __launch_bounds__(256) void k_dwgT(const u16* __restrict__ hp_, const float* __restrict__ w9,
                                              u16* __restrict__ ygT, int rows_loc, int band_px) {
  __shared__ u16 ld[64][523];
  const int b = blockIdx.y;
  const int p0 = blockIdx.x * 64;
  const int olr = p0 >> 8, col0 = p0 & 255;
  const int tid = threadIdx.x;
  if (tid < 128) {                     // zero pad channels 510,511
    int px = tid >> 1, c = 510 + (tid & 1);
    ld[px][c] = 0;
  }
  __syncthreads();
  for (int it = 0; it < 16; ++it) {
    int idx = it * 256 + tid;          // 4080 items: j(8) x c(510)
    if (idx >= HIDN * 8) break;
    int j = idx & 7, c = idx >> 3;
    const u16* ia = hp_ + (size_t)(b * OPAD + c) * rows_loc * 256;
    const u16* ig = hp_ + (size_t)(b * OPAD + c + HIDN) * rows_loc * 256;
    float aa[8] = {0.f,0.f,0.f,0.f,0.f,0.f,0.f,0.f};
    float gg[8] = {0.f,0.f,0.f,0.f,0.f,0.f,0.f,0.f};
    const int jm = col0 + j * 8;
    const bool hasL = jm > 0, hasR = jm < 248;
    #pragma unroll
    for (int dr = 0; dr < 3; ++dr) {
      dw3row(ia + (olr + dr) * 256, jm, hasL, hasR,
             w9[c * 9 + dr * 3], w9[c * 9 + dr * 3 + 1], w9[c * 9 + dr * 3 + 2], aa);
      dw3row(ig + (olr + dr) * 256, jm, hasL, hasR,
             w9[(c + HIDN) * 9 + dr * 3], w9[(c + HIDN) * 9 + dr * 3 + 1],
             w9[(c + HIDN) * 9 + dr * 3 + 2], gg);
    }
    #pragma unroll
    for (int i = 0; i < 8; ++i) {
      float a = aa[i];
      float gel = 0.5f * a * (1.f + erff(a * 0.70710678118654752f));
      ld[j * 8 + i][c] = f2bf(gel * gg[i]);
    }
  }
  __syncthreads();
  u16* Tb = ygT + ((size_t)b * band_px + p0) * 512;
  for (int it = 0; it < 16; ++it) {
    int idx = it * 256 + tid;
    int ch = idx & 63, pl = idx >> 6;
    union { u16 s[8]; uint4 v; } t;
    #pragma unroll
    for (int r = 0; r < 8; ++r) t.s[r] = ld[pl][ch * 8 + r];
    int sch = ch ^ (pl & 7);
    *(uint4*)((char*)(Tb + (size_t)pl * 512) + sch * 16) = t.v;
  }
}

// ---------- launch ----------
extern "C" void kernel_launch(void* const* d_in, const int* in_sizes, int n_in,
                              void* d_out, int out_size, void* d_ws, size_t ws_size,
                              hipStream_t stream) {
  const float* x       = (const float*)d_in[0];
  const float* n1_w    = (const float*)d_in[1];
  const float* n1_b    = (const float*)d_in[2];
  const float* qkv_w   = (const float*)d_in[3];
  const float* qkv_dw  = (const float*)d_in[4];
  const float* proj_w  = (const float*)d_in[5];
  const float* temp    = (const float*)d_in[6];
  const float* n2_w    = (const float*)d_in[7];
  const float* n2_b    = (const float*)d_in[8];
  const float* ff_in_w = (const float*)d_in[9];
  const float* ff_dw   = (const float*)d_in[10];
  const float* ff_out_w= (const float*)d_in[11];

  char* ws = (char*)d_ws;
  float* stats1 = (float*)(ws + OFF_STATS1);
  float* stats2 = (float*)(ws + OFF_STATS2);
  float* G      = (float*)(ws + OFF_G);
  float* nq     = (float*)(ws + OFF_NQ);
  float* nk     = (float*)(ws + OFF_NK);
  float* biasq  = (float*)(ws + OFF_BQ);
  float* bias2  = (float*)(ws + OFF_B2);
  u16*   Mb16   = (u16*)(ws + OFF_M);
  u16*   Wq     = (u16*)(ws + OFF_WQ);
  u16*   W2b    = (u16*)(ws + OFF_W2B);
  u16*   W3     = (u16*)(ws + OFF_W3);
  u16*   xT     = (u16*)(ws + OFF_T);      // xT -> vdwT -> x2T
  u16*   qkv    = (u16*)(ws + OFF_QKV);
  float* outp   = (float*)d_out;

  int NP = 32;
  const int cand[4] = {2, 4, 8, 16};
  for (int i = 0; i < 4; ++i) {
    int rws = 256 / cand[i], rl = rws + 2;
    size_t band = (size_t)2 * OPAD * rl * 256 * 2 + (size_t)2 * rws * 256 * 512 * 2;
    if (OFF_BAND + band + ((size_t)8 << 20) <= ws_size) { NP = cand[i]; break; }
  }
  const int rows = 256 / NP, rows_loc = rows + 2, band_px = rows * 256;
  u16* hpre = (u16*)(ws + OFF_BAND);
  u16* ygT  = (u16*)(ws + OFF_BAND + (size_t)2 * OPAD * rows_loc * 256 * 2);

  hipMemsetAsync(ws, 0, ZERO_BYTES, stream);

  // ---- attention ----
  k_stats<<<dim3(1024, BATCH), 256, 0, stream>>>(x, stats1);
  k_fold<<<dim3(OQKV, BATCH), CDIM, 0, stream>>>(qkv_w, n1_w, n1_b, stats1, Wq, biasq, OQKV);
  k_tr<<<dim3(NPIX / 128, BATCH), 256, 0, stream>>>(x, xT);
  k_mgemm<192, 192, 0, 0><<<dim3(OQKV / 64, NPIX / 128, BATCH), 256, 0, stream>>>(
      xT, Wq, biasq, nullptr, qkv, OQKV,
      (long)NPIX * CDIM, (long)OQKV * CDIM, (long)OQKV * NPIX, NPIX, 0, NPIX, 0, nullptr);
  k_gram<<<dim3(256, BATCH * NHEADS), 256, 0, stream>>>(qkv, qkv_dw, G, nq, nk);
  k_attnM<<<dim3(NHEADS, BATCH), 256, 0, stream>>>(G, nq, nk, temp, proj_w, Mb16);
  k_dwT<<<dim3(NPIX / 64, BATCH), 256, 0, stream>>>(qkv, qkv_dw, xT);   // vdwT over xT
  k_mgemm<192, 192, 1, 1><<<dim3(CDIM / 64, NPIX / 128, BATCH), 256, 0, stream>>>(
      xT, Mb16, nullptr, x, outp, CDIM,
      (long)NPIX * CDIM, (long)CDIM * CDIM, (long)CDIM * NPIX, NPIX, 0, NPIX, 0, stats2);

  // ---- GDFN ----
  k_tr<<<dim3(NPIX / 128, BATCH), 256, 0, stream>>>(outp, xT);   // x2T (reuse region)
  k_fold<<<dim3(OPAD, BATCH), CDIM, 0, stream>>>(ff_in_w, n2_w, n2_b, stats2, W2b, bias2, 1020);
  k_fold3<<<dim3(CDIM), 256, 0, stream>>>(ff_out_w, W3);
  for (int rp = 0; rp < NP; ++rp) {
    const int band0 = rp * band_px;
    k_mgemm<192, 192, 0, 0><<<dim3(OPAD / 64, rows_loc * 2, BATCH), 256, 0, stream>>>(
        xT, W2b, bias2, nullptr, hpre, OPAD,
        (long)NPIX * CDIM, (long)OPAD * CDIM, (long)OPAD * rows_loc * 256, rows_loc * 256,
        band0 - 256, NPIX, 0, nullptr);
    k_dwgT<<<dim3(band_px / 64, BATCH), 256, 0, stream>>>(hpre, ff_dw, ygT, rows_loc, band_px);
    k_mgemm<512, 256, 1, 0><<<dim3(CDIM / 64, rows * 2, BATCH), 256, 0, stream>>>(
        ygT, W3, nullptr, outp, outp, CDIM,
        (long)band_px * 512, 0L, (long)CDIM * NPIX, NPIX, 0, band_px, band0, nullptr);
  }
}